// Round 2
// baseline (207.498 us; speedup 1.0000x reference)
//
#include <hip/hip_runtime.h>
#include <hip/hip_bf16.h>

typedef unsigned short u16;
typedef short bf16x8 __attribute__((ext_vector_type(8)));
typedef float f32x4 __attribute__((ext_vector_type(4)));

#define S_LEN 2048
#define DQ 512
#define NBATCH 4

__device__ __forceinline__ u16 f2bf(float f) {
    __hip_bfloat16 h = __float2bfloat16(f);
    return *reinterpret_cast<u16*>(&h);
}
__device__ __forceinline__ float bf2f(u16 u) {
    unsigned v = ((unsigned)u) << 16;
    union { unsigned u; float f; } c; c.u = v; return c.f;
}

__device__ __forceinline__ void async16(const u16* g, u16* l) {
    __builtin_amdgcn_global_load_lds(
        (__attribute__((address_space(1))) void*)g,
        (__attribute__((address_space(3))) void*)l, 16, 0, 0);
}

// XCD-chunked bijective swizzle (T1): hardware assigns dispatch id d -> XCD d%8.
// Map d -> logical id so each XCD owns a CONTIGUOUS logical chunk; logical
// neighbors (which share A panels) then share one XCD's private L2.
// Requires nwg % 8 == 0 (all three GEMM grids satisfy this).
__device__ __forceinline__ int xcd_swz(int bid, int chunk) {
    return (bid & 7) * chunk + (bid >> 3);
}

// -------- fp32 -> bf16 convert: x + Wq + Wk + Wv; tail blocks zero the sums buffer --------
__global__ __launch_bounds__(256) void k_cvt_all(const float* __restrict__ x,
                                                 const float* __restrict__ wq,
                                                 const float* __restrict__ wk,
                                                 const float* __restrict__ wv,
                                                 u16* __restrict__ xb, u16* __restrict__ wb,
                                                 float* __restrict__ sums) {
    int bid = blockIdx.x;
    if (bid >= 4864) {  // 8 blocks zero sums[8192]
        int i = (bid - 4864) * 256 + threadIdx.x;
        *(f32x4*)(sums + (size_t)i * 4) = (f32x4)0.0f;
        return;
    }
    const float* src;
    u16* dst;
    int i;
    if (bid < 4096)      { src = x;  dst = xb;          i = bid * 256 + threadIdx.x; }
    else if (bid < 4352) { src = wq; dst = wb;          i = (bid - 4096) * 256 + threadIdx.x; }
    else if (bid < 4608) { src = wk; dst = wb + 262144; i = (bid - 4352) * 256 + threadIdx.x; }
    else                 { src = wv; dst = wb + 524288; i = (bid - 4608) * 256 + threadIdx.x; }
    f32x4 v = *(const f32x4*)(src + (size_t)i * 4);
    ushort4 o;
    o.x = f2bf(v.x); o.y = f2bf(v.y); o.z = f2bf(v.z); o.w = f2bf(v.w);
    *(ushort4*)(dst + (size_t)i * 4) = o;
}

// -------- shared 128x128 GEMM core (BK=32): C += A[128 x K] * B[128 x K]^T --------
__device__ __forceinline__ void gemm_core(const u16* __restrict__ A, const u16* __restrict__ B,
                                          int lda, int ldb, int kend,
                                          f32x4 acc[4][4], u16* ldsA, u16* ldsB, int tid) {
    const int lane = tid & 63;
    const int w    = tid >> 6;
    const int wm   = (w & 1) << 6;
    const int wn   = (w >> 1) << 6;
    const int l16  = lane & 15;
    const int quad = lane >> 4;

    for (int k0 = 0; k0 < kend; k0 += 32) {
#pragma unroll
        for (int i = 0; i < 2; ++i) {
            int c  = i * 256 + tid;        // chunk 0..511, 16B each
            int r  = c >> 2;               // row 0..127
            int cc = (c & 3) << 3;         // col element 0/8/16/24
            async16(A + (size_t)r * lda + k0 + cc, ldsA + r * 32 + cc);
            async16(B + (size_t)r * ldb + k0 + cc, ldsB + r * 32 + cc);
        }
        __syncthreads();
        bf16x8 af[4], bf[4];
#pragma unroll
        for (int i = 0; i < 4; ++i)
            af[i] = *(const bf16x8*)(ldsA + (wm + i * 16 + l16) * 32 + quad * 8);
#pragma unroll
        for (int j = 0; j < 4; ++j)
            bf[j] = *(const bf16x8*)(ldsB + (wn + j * 16 + l16) * 32 + quad * 8);
#pragma unroll
        for (int i = 0; i < 4; ++i)
#pragma unroll
            for (int j = 0; j < 4; ++j)
                acc[i][j] = __builtin_amdgcn_mfma_f32_16x16x32_bf16(af[i], bf[j], acc[i][j], 0, 0, 0);
        __syncthreads();
    }
}

// -------- projection: z in {Q,K,V}; Q,K -> row-major bf16; V -> transposed into VT --------
// 1D grid, nwg = 768 = (z=3) x (y=64) x (x=4); chunk = 96 per XCD.
__global__ __launch_bounds__(256) void k_proj(const u16* __restrict__ xb, const u16* __restrict__ Wb,
                                              const float* __restrict__ bq, const float* __restrict__ bk,
                                              const float* __restrict__ bv, u16* __restrict__ out,
                                              u16* __restrict__ VT) {
    __shared__ __align__(16) u16 lds[8192];
    const int l  = xcd_swz(blockIdx.x, 96);
    const int bx = l & 3;
    const int by = (l >> 2) & 63;
    const int z  = l >> 8;
    const int m0 = by * 128, n0 = bx * 128;
    const u16* A = xb + (size_t)m0 * DQ;
    const u16* B = Wb + (size_t)z * DQ * DQ + (size_t)n0 * DQ;
    const float* bias = (z == 0) ? bq : (z == 1) ? bk : bv;

    f32x4 acc[4][4];
#pragma unroll
    for (int i = 0; i < 4; ++i)
#pragma unroll
        for (int j = 0; j < 4; ++j) acc[i][j] = (f32x4)0.0f;

    int tid = threadIdx.x;
    gemm_core(A, B, DQ, DQ, DQ, acc, lds, lds + 4096, tid);

    const int lane = tid & 63, w = tid >> 6;
    const int wm = (w & 1) << 6, wn = (w >> 1) << 6;
    const int l16 = lane & 15, quad = lane >> 4;

    if (z < 2) {
        u16* outz = out + (size_t)z * 8192 * DQ;
#pragma unroll
        for (int j = 0; j < 4; ++j) {
            int gn = n0 + wn + j * 16 + l16;
            float bb = bias[gn];
#pragma unroll
            for (int i = 0; i < 4; ++i)
#pragma unroll
                for (int r = 0; r < 4; ++r) {
                    int gm = m0 + wm + i * 16 + quad * 4 + r;
                    outz[(size_t)gm * DQ + gn] = f2bf(acc[i][j][r] + bb);
                }
        }
    } else {
        // V: write transposed. token gm -> (b = gm>>11, t = gm&2047); feature gn -> VT row.
        const int b = m0 >> 11;                 // m-tile never crosses batch (128 | 2048)
        u16* VTb_ = VT + (size_t)b * DQ * S_LEN;
#pragma unroll
        for (int j = 0; j < 4; ++j) {
            int gn = n0 + wn + j * 16 + l16;
            float bb = bias[gn];
#pragma unroll
            for (int i = 0; i < 4; ++i) {
                int t0 = (m0 & 2047) + wm + i * 16 + quad * 4;
                ushort4 o;
                o.x = f2bf(acc[i][j][0] + bb);
                o.y = f2bf(acc[i][j][1] + bb);
                o.z = f2bf(acc[i][j][2] + bb);
                o.w = f2bf(acc[i][j][3] + bb);
                *(ushort4*)(VTb_ + (size_t)gn * S_LEN + t0) = o;
            }
        }
    }
}

// -------- scores: e = exp(QK^T * scale) -> bf16 into Pb + atomic partial row-sums --------
// Scores are bounded (|s| <~ 2.5 after 1/sqrt(512) scaling) -> exp safe without max pass.
// Partial sums accumulate the bf16-ROUNDED e (same values k_norm used to sum).
// 1D grid, nwg = 1024 = (z=4) x (y=16) x (x=16); chunk = 128 per XCD.
__global__ __launch_bounds__(256) void k_scores(const u16* __restrict__ Qb, const u16* __restrict__ Kb,
                                                u16* __restrict__ Pb, float* __restrict__ sums) {
    __shared__ __align__(16) u16 lds[8192];
    const int l  = xcd_swz(blockIdx.x, 128);
    const int bx = l & 15;
    const int by = (l >> 4) & 15;
    const int b  = l >> 8;
    const int m0 = by * 128, n0 = bx * 128;
    const u16* A = Qb + ((size_t)b * S_LEN + m0) * DQ;
    const u16* B = Kb + ((size_t)b * S_LEN + n0) * DQ;

    f32x4 acc[4][4];
#pragma unroll
    for (int i = 0; i < 4; ++i)
#pragma unroll
        for (int j = 0; j < 4; ++j) acc[i][j] = (f32x4)0.0f;

    int tid = threadIdx.x;
    gemm_core(A, B, DQ, DQ, DQ, acc, lds, lds + 4096, tid);

    const float scale = 0.044194173824159216f; // 1/sqrt(512)
    const int lane = tid & 63, w = tid >> 6;
    const int wm = (w & 1) << 6, wn = (w >> 1) << 6;
    const int l16 = lane & 15, quad = lane >> 4;
    u16* prow = Pb + (size_t)(b * S_LEN + m0) * S_LEN;

    float psum[4][4];
#pragma unroll
    for (int i = 0; i < 4; ++i)
#pragma unroll
        for (int r = 0; r < 4; ++r) psum[i][r] = 0.0f;

#pragma unroll
    for (int i = 0; i < 4; ++i)
#pragma unroll
        for (int j = 0; j < 4; ++j)
#pragma unroll
            for (int r = 0; r < 4; ++r) {
                int gm = wm + i * 16 + quad * 4 + r;
                int gn = n0 + wn + j * 16 + l16;
                float e = __expf(acc[i][j][r] * scale);
                u16 pb = f2bf(e);
                prow[(size_t)gm * S_LEN + gn] = pb;
                psum[i][r] += bf2f(pb);
            }

    // reduce the 4-col partials across the 16-lane group (l16 bits 0..3), then
    // one atomicAdd per (row, warp) -> 64 atomics/warp, 256/block.
    float* sums_row = sums + b * S_LEN + m0;
#pragma unroll
    for (int i = 0; i < 4; ++i)
#pragma unroll
        for (int r = 0; r < 4; ++r) {
            float v = psum[i][r];
            v += __shfl_xor(v, 1);
            v += __shfl_xor(v, 2);
            v += __shfl_xor(v, 4);
            v += __shfl_xor(v, 8);
            if (l16 == 0) atomicAdd(&sums_row[wm + i * 16 + quad * 4 + r], v);
        }
}

// -------- weighted = (e * V) * inv; also writes normalized fp32 probs from LDS --------
// 128x64 tiles, BK=64 as two 32-planes. 1D grid, nwg = 512 = (z=4) x (y=16) x (x=8);
// chunk = 64 per XCD -> the 8 n-blocks sharing each 512 KB Pb panel co-reside on one XCD.
// Each block streams the FULL 128x2048 P panel through LDS, so block bx also emits
// the normalized fp32 probs for columns [bx*256, bx*256+256) straight from LDS.
__global__ __launch_bounds__(256) void k_pv(const u16* __restrict__ Pb, const u16* __restrict__ VT,
                                            const float* __restrict__ sums,
                                            float* __restrict__ probs,
                                            float* __restrict__ wout) {
    // A: 2 planes x (128x32) u16 @ 0 / 4096; B: 2 planes x (64x32) u16 @ 8192 / 10240
    __shared__ __align__(16) u16 lds[12288];
    u16* ldsA = lds;
    u16* ldsB = lds + 8192;
    const int l  = xcd_swz(blockIdx.x, 64);
    const int bx = l & 7;
    const int by = (l >> 3) & 15;
    const int b  = l >> 7;
    const int m0 = by * 128, n0 = bx * 64;
    const u16* A = Pb + (size_t)(b * S_LEN + m0) * S_LEN;
    const u16* B = VT + (size_t)b * DQ * S_LEN + (size_t)n0 * S_LEN;

    const int tid  = threadIdx.x;
    const int lane = tid & 63;
    const int w    = tid >> 6;
    const int wm   = (w & 1) << 6;      // 0 / 64
    const int wn   = (w >> 1) << 5;     // 0 / 32
    const int l16  = lane & 15;
    const int quad = lane >> 4;

    // probs-write assignment: thread t owns row (t>>1), plane (t&1) -> 32 cols / iter
    const int  pr_row = tid >> 1;
    const int  pr_h   = tid & 1;
    const float pr_inv = 1.0f / sums[b * S_LEN + m0 + pr_row];
    float* probsb = probs + ((size_t)b * S_LEN + m0) * S_LEN;

    f32x4 acc[4][2];
#pragma unroll
    for (int i = 0; i < 4; ++i)
#pragma unroll
        for (int j = 0; j < 2; ++j) acc[i][j] = (f32x4)0.0f;

    for (int k0 = 0; k0 < S_LEN; k0 += 64) {
#pragma unroll
        for (int h = 0; h < 2; ++h) {
            // A plane h: 512 chunks of 16B
#pragma unroll
            for (int it = 0; it < 2; ++it) {
                int c  = it * 256 + tid;
                int r  = c >> 2;
                int cc = (c & 3) << 3;
                async16(A + (size_t)r * S_LEN + k0 + h * 32 + cc, ldsA + h * 4096 + r * 32 + cc);
            }
            // B plane h: 256 chunks
            {
                int r  = tid >> 2;
                int cc = (tid & 3) << 3;
                async16(B + (size_t)r * S_LEN + k0 + h * 32 + cc, ldsB + h * 2048 + r * 32 + cc);
            }
        }
        __syncthreads();
        bf16x8 af[2][4], bfr[2][2];
#pragma unroll
        for (int h = 0; h < 2; ++h) {
#pragma unroll
            for (int i = 0; i < 4; ++i)
                af[h][i] = *(const bf16x8*)(ldsA + h * 4096 + (wm + i * 16 + l16) * 32 + quad * 8);
#pragma unroll
            for (int j = 0; j < 2; ++j)
                bfr[h][j] = *(const bf16x8*)(ldsB + h * 2048 + (wn + j * 16 + l16) * 32 + quad * 8);
        }
#pragma unroll
        for (int h = 0; h < 2; ++h)
#pragma unroll
            for (int i = 0; i < 4; ++i)
#pragma unroll
                for (int j = 0; j < 2; ++j)
                    acc[i][j] = __builtin_amdgcn_mfma_f32_16x16x32_bf16(af[h][i], bfr[h][j], acc[i][j], 0, 0, 0);

        // normalized probs write for this block's assigned column range, from LDS
        if ((k0 >> 8) == bx) {
            const u16* src = ldsA + pr_h * 4096 + pr_row * 32;
            float* dst = probsb + (size_t)pr_row * S_LEN + k0 + pr_h * 32;
#pragma unroll
            for (int q = 0; q < 4; ++q) {
                bf16x8 vv = *(const bf16x8*)(src + q * 8);
                f32x4 o0, o1;
                o0.x = bf2f((u16)vv[0]) * pr_inv;
                o0.y = bf2f((u16)vv[1]) * pr_inv;
                o0.z = bf2f((u16)vv[2]) * pr_inv;
                o0.w = bf2f((u16)vv[3]) * pr_inv;
                o1.x = bf2f((u16)vv[4]) * pr_inv;
                o1.y = bf2f((u16)vv[5]) * pr_inv;
                o1.z = bf2f((u16)vv[6]) * pr_inv;
                o1.w = bf2f((u16)vv[7]) * pr_inv;
                *(f32x4*)(dst + q * 8) = o0;
                *(f32x4*)(dst + q * 8 + 4) = o1;
            }
        }
        __syncthreads();
    }

    const float* sumsb = sums + b * S_LEN;
    float* outb = wout + (size_t)b * S_LEN * DQ;
#pragma unroll
    for (int i = 0; i < 4; ++i) {
#pragma unroll
        for (int r = 0; r < 4; ++r) {
            int gm = m0 + wm + i * 16 + quad * 4 + r;
            float inv = 1.0f / sumsb[gm];
#pragma unroll
            for (int j = 0; j < 2; ++j) {
                int gn = n0 + wn + j * 16 + l16;
                outb[(size_t)gm * DQ + gn] = acc[i][j][r] * inv;
            }
        }
    }
}

extern "C" void kernel_launch(void* const* d_in, const int* in_sizes, int n_in,
                              void* d_out, int out_size, void* d_ws, size_t ws_size,
                              hipStream_t stream) {
    const float* x  = (const float*)d_in[0];
    const float* Wq = (const float*)d_in[1];
    const float* bq = (const float*)d_in[2];
    const float* Wk = (const float*)d_in[3];
    const float* bk = (const float*)d_in[4];
    const float* Wv = (const float*)d_in[5];
    const float* bv = (const float*)d_in[6];

    char* ws = (char*)d_ws;
    u16* xb  = (u16*)(ws);                 // x bf16        [8192][512]   8.39 MB
    u16* Wb  = (u16*)(ws + 8388608);       // Wq,Wk,Wv bf16 3x[512][512]  1.57 MB
    u16* Qb  = (u16*)(ws + 9961472);       // Q bf16        [8192][512]
    u16* Kb  = (u16*)(ws + 18350080);      // K bf16        [8192][512]
    u16* VTb = (u16*)(ws + 35127296);      // V^T bf16      [4][512][2048]
    u16* Pb  = (u16*)(ws + 43515904);      // e bf16 (unnormalized) [8192][2048]  33.6 MB
    float* sums = (float*)(ws + 77070336); // [8192] fp32 row sums (atomic)
    float* probs = (float*)d_out;                        // [4][2048][2048]
    float* wout  = (float*)d_out + 16777216;             // [4][2048][512]

    k_cvt_all<<<4872, 256, 0, stream>>>(x, Wq, Wk, Wv, xb, Wb, sums);
    k_proj<<<768, 256, 0, stream>>>(xb, Wb, bq, bk, bv, Qb, VTb);
    k_scores<<<1024, 256, 0, stream>>>(Qb, Kb, Pb, sums);
    k_pv<<<512, 256, 0, stream>>>(Pb, VTb, sums, probs, wout);
}

// Round 3
// 203.248 us; speedup vs baseline: 1.0209x; 1.0209x over previous
//
#include <hip/hip_runtime.h>
#include <hip/hip_bf16.h>

typedef unsigned short u16;
typedef short bf16x8 __attribute__((ext_vector_type(8)));
typedef float f32x4 __attribute__((ext_vector_type(4)));

#define S_LEN 2048
#define DQ 512
#define NBATCH 4

__device__ __forceinline__ u16 f2bf(float f) {
    __hip_bfloat16 h = __float2bfloat16(f);
    return *reinterpret_cast<u16*>(&h);
}
__device__ __forceinline__ float bf2f(u16 u) {
    unsigned v = ((unsigned)u) << 16;
    union { unsigned u; float f; } c; c.u = v; return c.f;
}

__device__ __forceinline__ void async16(const u16* g, u16* l) {
    __builtin_amdgcn_global_load_lds(
        (__attribute__((address_space(1))) void*)g,
        (__attribute__((address_space(3))) void*)l, 16, 0, 0);
}

// XCD-chunked bijective swizzle (T1): hardware assigns dispatch id d -> XCD d%8.
// Map d -> logical id so each XCD owns a CONTIGUOUS logical chunk; logical
// neighbors (which share A panels) then share one XCD's private L2.
// Requires nwg % 8 == 0 (all three GEMM grids satisfy this).
__device__ __forceinline__ int xcd_swz(int bid, int chunk) {
    return (bid & 7) * chunk + (bid >> 3);
}

// -------- fp32 -> bf16 convert: x + Wq + Wk + Wv; tail blocks zero the sums buffer --------
__global__ __launch_bounds__(256) void k_cvt_all(const float* __restrict__ x,
                                                 const float* __restrict__ wq,
                                                 const float* __restrict__ wk,
                                                 const float* __restrict__ wv,
                                                 u16* __restrict__ xb, u16* __restrict__ wb,
                                                 float* __restrict__ sums) {
    int bid = blockIdx.x;
    if (bid >= 4864) {  // 8 blocks zero sums[8192]
        int i = (bid - 4864) * 256 + threadIdx.x;
        *(f32x4*)(sums + (size_t)i * 4) = (f32x4)0.0f;
        return;
    }
    const float* src;
    u16* dst;
    int i;
    if (bid < 4096)      { src = x;  dst = xb;          i = bid * 256 + threadIdx.x; }
    else if (bid < 4352) { src = wq; dst = wb;          i = (bid - 4096) * 256 + threadIdx.x; }
    else if (bid < 4608) { src = wk; dst = wb + 262144; i = (bid - 4352) * 256 + threadIdx.x; }
    else                 { src = wv; dst = wb + 524288; i = (bid - 4608) * 256 + threadIdx.x; }
    f32x4 v = *(const f32x4*)(src + (size_t)i * 4);
    ushort4 o;
    o.x = f2bf(v.x); o.y = f2bf(v.y); o.z = f2bf(v.z); o.w = f2bf(v.w);
    *(ushort4*)(dst + (size_t)i * 4) = o;
}

// -------- shared 128x128 GEMM core (BK=32): C += A[128 x K] * B[128 x K]^T --------
__device__ __forceinline__ void gemm_core(const u16* __restrict__ A, const u16* __restrict__ B,
                                          int lda, int ldb, int kend,
                                          f32x4 acc[4][4], u16* ldsA, u16* ldsB, int tid) {
    const int lane = tid & 63;
    const int w    = tid >> 6;
    const int wm   = (w & 1) << 6;
    const int wn   = (w >> 1) << 6;
    const int l16  = lane & 15;
    const int quad = lane >> 4;

    for (int k0 = 0; k0 < kend; k0 += 32) {
#pragma unroll
        for (int i = 0; i < 2; ++i) {
            int c  = i * 256 + tid;        // chunk 0..511, 16B each
            int r  = c >> 2;               // row 0..127
            int cc = (c & 3) << 3;         // col element 0/8/16/24
            async16(A + (size_t)r * lda + k0 + cc, ldsA + r * 32 + cc);
            async16(B + (size_t)r * ldb + k0 + cc, ldsB + r * 32 + cc);
        }
        __syncthreads();
        bf16x8 af[4], bf[4];
#pragma unroll
        for (int i = 0; i < 4; ++i)
            af[i] = *(const bf16x8*)(ldsA + (wm + i * 16 + l16) * 32 + quad * 8);
#pragma unroll
        for (int j = 0; j < 4; ++j)
            bf[j] = *(const bf16x8*)(ldsB + (wn + j * 16 + l16) * 32 + quad * 8);
#pragma unroll
        for (int i = 0; i < 4; ++i)
#pragma unroll
            for (int j = 0; j < 4; ++j)
                acc[i][j] = __builtin_amdgcn_mfma_f32_16x16x32_bf16(af[i], bf[j], acc[i][j], 0, 0, 0);
        __syncthreads();
    }
}

// -------- projection: z in {Q,K,V}; Q,K -> row-major bf16; V -> transposed into VT --------
// 1D grid, nwg = 768 = (z=3) x (y=64) x (x=4); chunk = 96 per XCD.
__global__ __launch_bounds__(256) void k_proj(const u16* __restrict__ xb, const u16* __restrict__ Wb,
                                              const float* __restrict__ bq, const float* __restrict__ bk,
                                              const float* __restrict__ bv, u16* __restrict__ out,
                                              u16* __restrict__ VT) {
    __shared__ __align__(16) u16 lds[8192];
    const int l  = xcd_swz(blockIdx.x, 96);
    const int bx = l & 3;
    const int by = (l >> 2) & 63;
    const int z  = l >> 8;
    const int m0 = by * 128, n0 = bx * 128;
    const u16* A = xb + (size_t)m0 * DQ;
    const u16* B = Wb + (size_t)z * DQ * DQ + (size_t)n0 * DQ;
    const float* bias = (z == 0) ? bq : (z == 1) ? bk : bv;

    f32x4 acc[4][4];
#pragma unroll
    for (int i = 0; i < 4; ++i)
#pragma unroll
        for (int j = 0; j < 4; ++j) acc[i][j] = (f32x4)0.0f;

    int tid = threadIdx.x;
    gemm_core(A, B, DQ, DQ, DQ, acc, lds, lds + 4096, tid);

    const int lane = tid & 63, w = tid >> 6;
    const int wm = (w & 1) << 6, wn = (w >> 1) << 6;
    const int l16 = lane & 15, quad = lane >> 4;

    if (z < 2) {
        u16* outz = out + (size_t)z * 8192 * DQ;
#pragma unroll
        for (int j = 0; j < 4; ++j) {
            int gn = n0 + wn + j * 16 + l16;
            float bb = bias[gn];
#pragma unroll
            for (int i = 0; i < 4; ++i)
#pragma unroll
                for (int r = 0; r < 4; ++r) {
                    int gm = m0 + wm + i * 16 + quad * 4 + r;
                    outz[(size_t)gm * DQ + gn] = f2bf(acc[i][j][r] + bb);
                }
        }
    } else {
        // V: write transposed. token gm -> (b = gm>>11, t = gm&2047); feature gn -> VT row.
        const int b = m0 >> 11;                 // m-tile never crosses batch (128 | 2048)
        u16* VTb_ = VT + (size_t)b * DQ * S_LEN;
#pragma unroll
        for (int j = 0; j < 4; ++j) {
            int gn = n0 + wn + j * 16 + l16;
            float bb = bias[gn];
#pragma unroll
            for (int i = 0; i < 4; ++i) {
                int t0 = (m0 & 2047) + wm + i * 16 + quad * 4;
                ushort4 o;
                o.x = f2bf(acc[i][j][0] + bb);
                o.y = f2bf(acc[i][j][1] + bb);
                o.z = f2bf(acc[i][j][2] + bb);
                o.w = f2bf(acc[i][j][3] + bb);
                *(ushort4*)(VTb_ + (size_t)gn * S_LEN + t0) = o;
            }
        }
    }
}

// -------- scores: e = exp(QK^T * scale) -> bf16 into Pb + atomic partial row-sums --------
// Scores are bounded (|s| <~ 2.5 after 1/sqrt(512) scaling) -> exp safe without max pass.
// Partial sums accumulate the bf16-ROUNDED e (same values k_norm used to sum).
// 1D grid, nwg = 1024 = (z=4) x (y=16) x (x=16); chunk = 128 per XCD.
__global__ __launch_bounds__(256) void k_scores(const u16* __restrict__ Qb, const u16* __restrict__ Kb,
                                                u16* __restrict__ Pb, float* __restrict__ sums) {
    __shared__ __align__(16) u16 lds[8192];
    const int l  = xcd_swz(blockIdx.x, 128);
    const int bx = l & 15;
    const int by = (l >> 4) & 15;
    const int b  = l >> 8;
    const int m0 = by * 128, n0 = bx * 128;
    const u16* A = Qb + ((size_t)b * S_LEN + m0) * DQ;
    const u16* B = Kb + ((size_t)b * S_LEN + n0) * DQ;

    f32x4 acc[4][4];
#pragma unroll
    for (int i = 0; i < 4; ++i)
#pragma unroll
        for (int j = 0; j < 4; ++j) acc[i][j] = (f32x4)0.0f;

    int tid = threadIdx.x;
    gemm_core(A, B, DQ, DQ, DQ, acc, lds, lds + 4096, tid);

    const float scale = 0.044194173824159216f; // 1/sqrt(512)
    const int lane = tid & 63, w = tid >> 6;
    const int wm = (w & 1) << 6, wn = (w >> 1) << 6;
    const int l16 = lane & 15, quad = lane >> 4;
    u16* prow = Pb + (size_t)(b * S_LEN + m0) * S_LEN;

    float psum[4][4];
#pragma unroll
    for (int i = 0; i < 4; ++i)
#pragma unroll
        for (int r = 0; r < 4; ++r) psum[i][r] = 0.0f;

#pragma unroll
    for (int i = 0; i < 4; ++i)
#pragma unroll
        for (int j = 0; j < 4; ++j)
#pragma unroll
            for (int r = 0; r < 4; ++r) {
                int gm = wm + i * 16 + quad * 4 + r;
                int gn = n0 + wn + j * 16 + l16;
                float e = __expf(acc[i][j][r] * scale);
                u16 pb = f2bf(e);
                prow[(size_t)gm * S_LEN + gn] = pb;
                psum[i][r] += bf2f(pb);
            }

    // reduce the 4-col partials across the 16-lane group (l16 bits 0..3), then
    // one atomicAdd per (row, warp) -> 64 atomics/warp, 256/block.
    float* sums_row = sums + b * S_LEN + m0;
#pragma unroll
    for (int i = 0; i < 4; ++i)
#pragma unroll
        for (int r = 0; r < 4; ++r) {
            float v = psum[i][r];
            v += __shfl_xor(v, 1);
            v += __shfl_xor(v, 2);
            v += __shfl_xor(v, 4);
            v += __shfl_xor(v, 8);
            if (l16 == 0) atomicAdd(&sums_row[wm + i * 16 + quad * 4 + r], v);
        }
}

// -------- weighted = (e * V) * inv; probs written post-loop from GLOBAL Pb (L2-hot) --------
// 128x64 tiles, BK=64 as two 32-planes. 1D grid, nwg = 512 = (z=4) x (y=16) x (x=8);
// chunk = 64 per XCD -> the 8 n-blocks sharing each 512 KB Pb panel co-reside on one XCD.
// Block bx also emits normalized fp32 probs for its 128x256 col-slice AFTER the K-loop,
// reading Pb from global (L2-resident on this XCD) -> coalesced, no LDS, no barriers.
__global__ __launch_bounds__(256) void k_pv(const u16* __restrict__ Pb, const u16* __restrict__ VT,
                                            const float* __restrict__ sums,
                                            float* __restrict__ probs,
                                            float* __restrict__ wout) {
    // A: 2 planes x (128x32) u16 @ 0 / 4096; B: 2 planes x (64x32) u16 @ 8192 / 10240
    __shared__ __align__(16) u16 lds[12288];
    u16* ldsA = lds;
    u16* ldsB = lds + 8192;
    const int l  = xcd_swz(blockIdx.x, 64);
    const int bx = l & 7;
    const int by = (l >> 3) & 15;
    const int b  = l >> 7;
    const int m0 = by * 128, n0 = bx * 64;
    const u16* A = Pb + (size_t)(b * S_LEN + m0) * S_LEN;
    const u16* B = VT + (size_t)b * DQ * S_LEN + (size_t)n0 * S_LEN;

    const int tid  = threadIdx.x;
    const int lane = tid & 63;
    const int w    = tid >> 6;
    const int wm   = (w & 1) << 6;      // 0 / 64
    const int wn   = (w >> 1) << 5;     // 0 / 32
    const int l16  = lane & 15;
    const int quad = lane >> 4;

    f32x4 acc[4][2];
#pragma unroll
    for (int i = 0; i < 4; ++i)
#pragma unroll
        for (int j = 0; j < 2; ++j) acc[i][j] = (f32x4)0.0f;

    for (int k0 = 0; k0 < S_LEN; k0 += 64) {
#pragma unroll
        for (int h = 0; h < 2; ++h) {
            // A plane h: 512 chunks of 16B
#pragma unroll
            for (int it = 0; it < 2; ++it) {
                int c  = it * 256 + tid;
                int r  = c >> 2;
                int cc = (c & 3) << 3;
                async16(A + (size_t)r * S_LEN + k0 + h * 32 + cc, ldsA + h * 4096 + r * 32 + cc);
            }
            // B plane h: 256 chunks
            {
                int r  = tid >> 2;
                int cc = (tid & 3) << 3;
                async16(B + (size_t)r * S_LEN + k0 + h * 32 + cc, ldsB + h * 2048 + r * 32 + cc);
            }
        }
        __syncthreads();
        bf16x8 af[2][4], bfr[2][2];
#pragma unroll
        for (int h = 0; h < 2; ++h) {
#pragma unroll
            for (int i = 0; i < 4; ++i)
                af[h][i] = *(const bf16x8*)(ldsA + h * 4096 + (wm + i * 16 + l16) * 32 + quad * 8);
#pragma unroll
            for (int j = 0; j < 2; ++j)
                bfr[h][j] = *(const bf16x8*)(ldsB + h * 2048 + (wn + j * 16 + l16) * 32 + quad * 8);
        }
#pragma unroll
        for (int h = 0; h < 2; ++h)
#pragma unroll
            for (int i = 0; i < 4; ++i)
#pragma unroll
                for (int j = 0; j < 2; ++j)
                    acc[i][j] = __builtin_amdgcn_mfma_f32_16x16x32_bf16(af[h][i], bfr[h][j], acc[i][j], 0, 0, 0);
        __syncthreads();
    }

    // inv table: 128 floats in LDS (reused), broadcast-read -> conflict-free
    float* ldsInv = (float*)lds;
    if (tid < 128) ldsInv[tid] = 1.0f / sums[b * S_LEN + m0 + tid];
    __syncthreads();

    float* outb = wout + (size_t)b * S_LEN * DQ;
#pragma unroll
    for (int i = 0; i < 4; ++i) {
#pragma unroll
        for (int r = 0; r < 4; ++r) {
            int lm = wm + i * 16 + quad * 4 + r;   // row within panel
            float inv = ldsInv[lm];
#pragma unroll
            for (int j = 0; j < 2; ++j) {
                int gn = n0 + wn + j * 16 + l16;
                outb[(size_t)(m0 + lm) * DQ + gn] = acc[i][j][r] * inv;
            }
        }
    }

    // normalized probs for this block's 128x256 col-slice, straight from global Pb (L2)
    const u16* Psl = Pb + (size_t)(b * S_LEN + m0) * S_LEN + bx * 256;
    float* Pro = probs + ((size_t)b * S_LEN + m0) * S_LEN + bx * 256;
#pragma unroll
    for (int it = 0; it < 16; ++it) {
        int idx = it * 256 + tid;       // 4096 chunks of 8 elems
        int r  = idx >> 5;              // row 0..127
        int cc = (idx & 31) << 3;       // col 0..255 step 8
        float inv = ldsInv[r];
        bf16x8 vv = *(const bf16x8*)(Psl + (size_t)r * S_LEN + cc);
        f32x4 o0, o1;
        o0.x = bf2f((u16)vv[0]) * inv;
        o0.y = bf2f((u16)vv[1]) * inv;
        o0.z = bf2f((u16)vv[2]) * inv;
        o0.w = bf2f((u16)vv[3]) * inv;
        o1.x = bf2f((u16)vv[4]) * inv;
        o1.y = bf2f((u16)vv[5]) * inv;
        o1.z = bf2f((u16)vv[6]) * inv;
        o1.w = bf2f((u16)vv[7]) * inv;
        float* dst = Pro + (size_t)r * S_LEN + cc;
        *(f32x4*)(dst) = o0;
        *(f32x4*)(dst + 4) = o1;
    }
}

extern "C" void kernel_launch(void* const* d_in, const int* in_sizes, int n_in,
                              void* d_out, int out_size, void* d_ws, size_t ws_size,
                              hipStream_t stream) {
    const float* x  = (const float*)d_in[0];
    const float* Wq = (const float*)d_in[1];
    const float* bq = (const float*)d_in[2];
    const float* Wk = (const float*)d_in[3];
    const float* bk = (const float*)d_in[4];
    const float* Wv = (const float*)d_in[5];
    const float* bv = (const float*)d_in[6];

    char* ws = (char*)d_ws;
    u16* xb  = (u16*)(ws);                 // x bf16        [8192][512]   8.39 MB
    u16* Wb  = (u16*)(ws + 8388608);       // Wq,Wk,Wv bf16 3x[512][512]  1.57 MB
    u16* Qb  = (u16*)(ws + 9961472);       // Q bf16        [8192][512]
    u16* Kb  = (u16*)(ws + 18350080);      // K bf16        [8192][512]
    u16* VTb = (u16*)(ws + 35127296);      // V^T bf16      [4][512][2048]
    u16* Pb  = (u16*)(ws + 43515904);      // e bf16 (unnormalized) [8192][2048]  33.6 MB
    float* sums = (float*)(ws + 77070336); // [8192] fp32 row sums (atomic)
    float* probs = (float*)d_out;                        // [4][2048][2048]
    float* wout  = (float*)d_out + 16777216;             // [4][2048][512]

    k_cvt_all<<<4872, 256, 0, stream>>>(x, Wq, Wk, Wv, xb, Wb, sums);
    k_proj<<<768, 256, 0, stream>>>(xb, Wb, bq, bk, bv, Qb, VTb);
    k_scores<<<1024, 256, 0, stream>>>(Qb, Kb, Pb, sums);
    k_pv<<<512, 256, 0, stream>>>(Pb, VTb, sums, probs, wout);
}

// Round 4
// 192.986 us; speedup vs baseline: 1.0752x; 1.0532x over previous
//
#include <hip/hip_runtime.h>
#include <hip/hip_bf16.h>

typedef unsigned short u16;
typedef short bf16x8 __attribute__((ext_vector_type(8)));
typedef float f32x4 __attribute__((ext_vector_type(4)));

#define S_LEN 2048
#define DQ 512
#define NBATCH 4

__device__ __forceinline__ u16 f2bf(float f) {
    __hip_bfloat16 h = __float2bfloat16(f);
    return *reinterpret_cast<u16*>(&h);
}
__device__ __forceinline__ float bf2f(u16 u) {
    unsigned v = ((unsigned)u) << 16;
    union { unsigned u; float f; } c; c.u = v; return c.f;
}

__device__ __forceinline__ void async16(const u16* g, u16* l) {
    __builtin_amdgcn_global_load_lds(
        (__attribute__((address_space(1))) void*)g,
        (__attribute__((address_space(3))) void*)l, 16, 0, 0);
}

// XCD-chunked bijective swizzle (T1): hardware assigns dispatch id d -> XCD d%8.
__device__ __forceinline__ int xcd_swz(int bid, int chunk) {
    return (bid & 7) * chunk + (bid >> 3);
}

// -------- fp32 -> bf16 convert: x + Wq + Wk + Wv; tail blocks zero the sums buffer --------
__global__ __launch_bounds__(256) void k_cvt_all(const float* __restrict__ x,
                                                 const float* __restrict__ wq,
                                                 const float* __restrict__ wk,
                                                 const float* __restrict__ wv,
                                                 u16* __restrict__ xb, u16* __restrict__ wb,
                                                 float* __restrict__ sums) {
    int bid = blockIdx.x;
    if (bid >= 4864) {  // 8 blocks zero sums[8192]
        int i = (bid - 4864) * 256 + threadIdx.x;
        *(f32x4*)(sums + (size_t)i * 4) = (f32x4)0.0f;
        return;
    }
    const float* src;
    u16* dst;
    int i;
    if (bid < 4096)      { src = x;  dst = xb;          i = bid * 256 + threadIdx.x; }
    else if (bid < 4352) { src = wq; dst = wb;          i = (bid - 4096) * 256 + threadIdx.x; }
    else if (bid < 4608) { src = wk; dst = wb + 262144; i = (bid - 4352) * 256 + threadIdx.x; }
    else                 { src = wv; dst = wb + 524288; i = (bid - 4608) * 256 + threadIdx.x; }
    f32x4 v = *(const f32x4*)(src + (size_t)i * 4);
    ushort4 o;
    o.x = f2bf(v.x); o.y = f2bf(v.y); o.z = f2bf(v.z); o.w = f2bf(v.w);
    *(ushort4*)(dst + (size_t)i * 4) = o;
}

// ================= 256x256 double-buffered GEMM core (BK=64, 8 waves) =================
// LDS layout per matrix buffer: [256 rows][64 cols] bf16, 128 B/row = 8 chunks of 16 B.
// XOR swizzle (T2/st-16x32): physical chunk = logical chunk ^ (row & 7).
// Staged via global_load_lds with LINEAR LDS dest + pre-swizzled GLOBAL source (rule 21).
// One half-tile (128 rows x 64 cols of one matrix) = 2 loads/thread.
__device__ __forceinline__ void stage_unit(const u16* __restrict__ G, u16* buf,
                                           int kcol, int h, int tid) {
#pragma unroll
    for (int q = 0; q < 2; ++q) {
        int c   = q * 512 + tid;          // 16B chunk id 0..1023 within half-tile
        int r   = c >> 3;                 // row 0..127 within half
        int p   = c & 7;                  // physical chunk within row
        int lch = p ^ (r & 7);            // logical (global) chunk
        async16(G + (size_t)(h * 128 + r) * DQ + kcol + lch * 8,
                buf + h * 8192 + c * 8);  // linear dest: wave-uniform base + lane*16B
    }
}

// A,B: row-major panels [256][512] (row stride DQ). C = A * B^T on 256x256 tile.
// acc[8][4]: wave (wr=w>>2, wc=w&3) owns rows wr*128..+127, cols wc*64..+63.
__device__ __forceinline__ void gemm256(const u16* __restrict__ A, const u16* __restrict__ B,
                                        u16* ldsA, u16* ldsB, f32x4 acc[8][4], int tid) {
    const int lane = tid & 63;
    const int w    = tid >> 6;
    const int wr   = w >> 2;
    const int wc   = w & 3;
    const int l16  = lane & 15;
    const int quad = lane >> 4;
    const int p0   = quad ^ (l16 & 7);       // physical chunk for k-slot 0 (row&7 == l16&7)
    const int a0   = (wr * 128 + l16) * 64 + p0 * 8;
    const int a1   = (wr * 128 + l16) * 64 + (p0 ^ 4) * 8;
    const int b0   = (wc * 64 + l16) * 64 + p0 * 8;
    const int b1   = (wc * 64 + l16) * 64 + (p0 ^ 4) * 8;

    // prologue: stage kt=0 into buffer 0
    stage_unit(A, ldsA, 0, 0, tid);
    stage_unit(A, ldsA, 0, 1, tid);
    stage_unit(B, ldsB, 0, 0, tid);
    stage_unit(B, ldsB, 0, 1, tid);
    __syncthreads();

    for (int kt = 0; kt < 8; ++kt) {
        const u16* rdA = ldsA + (kt & 1) * 16384;
        const u16* rdB = ldsB + (kt & 1) * 16384;
        u16* wrA = ldsA + ((kt + 1) & 1) * 16384;
        u16* wrB = ldsB + ((kt + 1) & 1) * 16384;
        const int  kc = (kt + 1) * 64;
        const bool pf = kt < 7;
        bf16x8 a[4][2], bbf[2][2];

        // ---- G0: prefetch A-half0(kt+1); read A m0-3 + B n0-1; MFMA ----
        if (pf) stage_unit(A, wrA, kc, 0, tid);
#pragma unroll
        for (int i = 0; i < 4; ++i) {
            a[i][0] = *(const bf16x8*)(rdA + a0 + i * 1024);
            a[i][1] = *(const bf16x8*)(rdA + a1 + i * 1024);
        }
#pragma unroll
        for (int j = 0; j < 2; ++j) {
            bbf[j][0] = *(const bf16x8*)(rdB + b0 + j * 1024);
            bbf[j][1] = *(const bf16x8*)(rdB + b1 + j * 1024);
        }
        __builtin_amdgcn_s_setprio(1);
#pragma unroll
        for (int i = 0; i < 4; ++i)
#pragma unroll
            for (int j = 0; j < 2; ++j) {
                acc[i][j] = __builtin_amdgcn_mfma_f32_16x16x32_bf16(a[i][0], bbf[j][0], acc[i][j], 0, 0, 0);
                acc[i][j] = __builtin_amdgcn_mfma_f32_16x16x32_bf16(a[i][1], bbf[j][1], acc[i][j], 0, 0, 0);
            }
        __builtin_amdgcn_s_setprio(0);

        // ---- G1: prefetch A-half1(kt+1); read B n2-3; MFMA m0-3 x n2-3 ----
        if (pf) stage_unit(A, wrA, kc, 1, tid);
#pragma unroll
        for (int j = 0; j < 2; ++j) {
            bbf[j][0] = *(const bf16x8*)(rdB + b0 + (2 + j) * 1024);
            bbf[j][1] = *(const bf16x8*)(rdB + b1 + (2 + j) * 1024);
        }
        __builtin_amdgcn_s_setprio(1);
#pragma unroll
        for (int i = 0; i < 4; ++i)
#pragma unroll
            for (int j = 0; j < 2; ++j) {
                acc[i][2 + j] = __builtin_amdgcn_mfma_f32_16x16x32_bf16(a[i][0], bbf[j][0], acc[i][2 + j], 0, 0, 0);
                acc[i][2 + j] = __builtin_amdgcn_mfma_f32_16x16x32_bf16(a[i][1], bbf[j][1], acc[i][2 + j], 0, 0, 0);
            }
        __builtin_amdgcn_s_setprio(0);

        // ---- G2: prefetch B-half0(kt+1); read A m4-7; MFMA m4-7 x n2-3 ----
        if (pf) stage_unit(B, wrB, kc, 0, tid);
#pragma unroll
        for (int i = 0; i < 4; ++i) {
            a[i][0] = *(const bf16x8*)(rdA + a0 + (4 + i) * 1024);
            a[i][1] = *(const bf16x8*)(rdA + a1 + (4 + i) * 1024);
        }
        __builtin_amdgcn_s_setprio(1);
#pragma unroll
        for (int i = 0; i < 4; ++i)
#pragma unroll
            for (int j = 0; j < 2; ++j) {
                acc[4 + i][2 + j] = __builtin_amdgcn_mfma_f32_16x16x32_bf16(a[i][0], bbf[j][0], acc[4 + i][2 + j], 0, 0, 0);
                acc[4 + i][2 + j] = __builtin_amdgcn_mfma_f32_16x16x32_bf16(a[i][1], bbf[j][1], acc[4 + i][2 + j], 0, 0, 0);
            }
        __builtin_amdgcn_s_setprio(0);

        // ---- G3: prefetch B-half1(kt+1); read B n0-1 again; MFMA m4-7 x n0-1 ----
        if (pf) stage_unit(B, wrB, kc, 1, tid);
#pragma unroll
        for (int j = 0; j < 2; ++j) {
            bbf[j][0] = *(const bf16x8*)(rdB + b0 + j * 1024);
            bbf[j][1] = *(const bf16x8*)(rdB + b1 + j * 1024);
        }
        __builtin_amdgcn_s_setprio(1);
#pragma unroll
        for (int i = 0; i < 4; ++i)
#pragma unroll
            for (int j = 0; j < 2; ++j) {
                acc[4 + i][j] = __builtin_amdgcn_mfma_f32_16x16x32_bf16(a[i][0], bbf[j][0], acc[4 + i][j], 0, 0, 0);
                acc[4 + i][j] = __builtin_amdgcn_mfma_f32_16x16x32_bf16(a[i][1], bbf[j][1], acc[4 + i][j], 0, 0, 0);
            }
        __builtin_amdgcn_s_setprio(0);

        // single drain barrier per K-tile: waits own-wave stage DMAs (vmcnt) + ds reads
        __syncthreads();
    }
}

// -------- projection: z in {Q,K,V}; 256x256 tiles; nwg = 192 = (z=3)x(by=32)x(bx=2) --------
__global__ __launch_bounds__(512, 2) void k_proj(const u16* __restrict__ xb, const u16* __restrict__ Wb,
                                                 const float* __restrict__ bq, const float* __restrict__ bk,
                                                 const float* __restrict__ bv, u16* __restrict__ out,
                                                 u16* __restrict__ VT) {
    __shared__ __align__(16) u16 lds[65536];   // 128 KiB: A 2x16384 | B 2x16384
    const int l  = xcd_swz(blockIdx.x, 24);
    const int bx = l & 1;
    const int by = (l >> 1) & 31;
    const int z  = l >> 6;
    const int m0 = by * 256, n0 = bx * 256;
    const u16* A = xb + (size_t)m0 * DQ;
    const u16* B = Wb + (size_t)z * DQ * DQ + (size_t)n0 * DQ;
    const float* bias = (z == 0) ? bq : (z == 1) ? bk : bv;

    f32x4 acc[8][4];
#pragma unroll
    for (int i = 0; i < 8; ++i)
#pragma unroll
        for (int j = 0; j < 4; ++j) acc[i][j] = (f32x4)0.0f;

    const int tid = threadIdx.x;
    gemm256(A, B, lds, lds + 32768, acc, tid);

    const int lane = tid & 63, w = tid >> 6;
    const int wr = w >> 2, wc = w & 3;
    const int l16 = lane & 15, quad = lane >> 4;

    if (z < 2) {
        u16* outz = out + (size_t)z * 8192 * DQ;
#pragma unroll
        for (int j = 0; j < 4; ++j) {
            int gn = n0 + wc * 64 + j * 16 + l16;
            float bv_ = bias[gn];
#pragma unroll
            for (int i = 0; i < 8; ++i)
#pragma unroll
                for (int r = 0; r < 4; ++r) {
                    int gm = m0 + wr * 128 + i * 16 + quad * 4 + r;
                    outz[(size_t)gm * DQ + gn] = f2bf(acc[i][j][r] + bv_);
                }
        }
    } else {
        // V transposed: 256-row tile never crosses batch (256 | 2048)
        const int bb_ = m0 >> 11;
        u16* VTb_ = VT + (size_t)bb_ * DQ * S_LEN;
#pragma unroll
        for (int j = 0; j < 4; ++j) {
            int gn = n0 + wc * 64 + j * 16 + l16;
            float bv_ = bias[gn];
#pragma unroll
            for (int i = 0; i < 8; ++i) {
                int t0 = (m0 & 2047) + wr * 128 + i * 16 + quad * 4;
                ushort4 o;
                o.x = f2bf(acc[i][j][0] + bv_);
                o.y = f2bf(acc[i][j][1] + bv_);
                o.z = f2bf(acc[i][j][2] + bv_);
                o.w = f2bf(acc[i][j][3] + bv_);
                *(ushort4*)(VTb_ + (size_t)gn * S_LEN + t0) = o;
            }
        }
    }
}

// -------- scores: 256x256 tiles; e=exp(QK^T*scale)->bf16 Pb + atomic row sums --------
// nwg = 256 = (b=4)x(by=8)x(bx=8); chunk 32/XCD -> Q 1MB + K 2MB per XCD (L2-fit).
__global__ __launch_bounds__(512, 2) void k_scores(const u16* __restrict__ Qb, const u16* __restrict__ Kb,
                                                   u16* __restrict__ Pb, float* __restrict__ sums) {
    __shared__ __align__(16) u16 lds[65536];
    const int l  = xcd_swz(blockIdx.x, 32);
    const int bx = l & 7;
    const int by = (l >> 3) & 7;
    const int b  = l >> 6;
    const int m0 = by * 256, n0 = bx * 256;
    const u16* A = Qb + ((size_t)b * S_LEN + m0) * DQ;
    const u16* B = Kb + ((size_t)b * S_LEN + n0) * DQ;

    f32x4 acc[8][4];
#pragma unroll
    for (int i = 0; i < 8; ++i)
#pragma unroll
        for (int j = 0; j < 4; ++j) acc[i][j] = (f32x4)0.0f;

    const int tid = threadIdx.x;
    gemm256(A, B, lds, lds + 32768, acc, tid);

    const float scale = 0.044194173824159216f; // 1/sqrt(512)
    const int lane = tid & 63, w = tid >> 6;
    const int wr = w >> 2, wc = w & 3;
    const int l16 = lane & 15, quad = lane >> 4;
    u16* prow = Pb + (size_t)(b * S_LEN + m0) * S_LEN;

    float psum[8][4];
#pragma unroll
    for (int i = 0; i < 8; ++i)
#pragma unroll
        for (int r = 0; r < 4; ++r) psum[i][r] = 0.0f;

#pragma unroll
    for (int i = 0; i < 8; ++i)
#pragma unroll
        for (int j = 0; j < 4; ++j)
#pragma unroll
            for (int r = 0; r < 4; ++r) {
                int gm = wr * 128 + i * 16 + quad * 4 + r;
                int gn = n0 + wc * 64 + j * 16 + l16;
                float e = __expf(acc[i][j][r] * scale);
                u16 pbv = f2bf(e);
                prow[(size_t)gm * S_LEN + gn] = pbv;
                psum[i][r] += bf2f(pbv);
            }

    float* sums_row = sums + b * S_LEN + m0 + wr * 128;
#pragma unroll
    for (int i = 0; i < 8; ++i)
#pragma unroll
        for (int r = 0; r < 4; ++r) {
            float v = psum[i][r];
            v += __shfl_xor(v, 1);
            v += __shfl_xor(v, 2);
            v += __shfl_xor(v, 4);
            v += __shfl_xor(v, 8);
            if (l16 == 0) atomicAdd(&sums_row[i * 16 + quad * 4 + r], v);
        }
}

// -------- weighted = (e * V) * inv; probs written post-loop from GLOBAL Pb (L2-hot) --------
// unchanged from round 3 (128x64 tiles, BK=64 two-plane; N=512 too narrow for 256^2).
__global__ __launch_bounds__(256) void k_pv(const u16* __restrict__ Pb, const u16* __restrict__ VT,
                                            const float* __restrict__ sums,
                                            float* __restrict__ probs,
                                            float* __restrict__ wout) {
    __shared__ __align__(16) u16 lds[12288];
    u16* ldsA = lds;
    u16* ldsB = lds + 8192;
    const int l  = xcd_swz(blockIdx.x, 64);
    const int bx = l & 7;
    const int by = (l >> 3) & 15;
    const int b  = l >> 7;
    const int m0 = by * 128, n0 = bx * 64;
    const u16* A = Pb + (size_t)(b * S_LEN + m0) * S_LEN;
    const u16* B = VT + (size_t)b * DQ * S_LEN + (size_t)n0 * S_LEN;

    const int tid  = threadIdx.x;
    const int lane = tid & 63;
    const int w    = tid >> 6;
    const int wm   = (w & 1) << 6;
    const int wn   = (w >> 1) << 5;
    const int l16  = lane & 15;
    const int quad = lane >> 4;

    f32x4 acc[4][2];
#pragma unroll
    for (int i = 0; i < 4; ++i)
#pragma unroll
        for (int j = 0; j < 2; ++j) acc[i][j] = (f32x4)0.0f;

    for (int k0 = 0; k0 < S_LEN; k0 += 64) {
#pragma unroll
        for (int h = 0; h < 2; ++h) {
#pragma unroll
            for (int it = 0; it < 2; ++it) {
                int c  = it * 256 + tid;
                int r  = c >> 2;
                int cc = (c & 3) << 3;
                async16(A + (size_t)r * S_LEN + k0 + h * 32 + cc, ldsA + h * 4096 + r * 32 + cc);
            }
            {
                int r  = tid >> 2;
                int cc = (tid & 3) << 3;
                async16(B + (size_t)r * S_LEN + k0 + h * 32 + cc, ldsB + h * 2048 + r * 32 + cc);
            }
        }
        __syncthreads();
        bf16x8 af[2][4], bfr[2][2];
#pragma unroll
        for (int h = 0; h < 2; ++h) {
#pragma unroll
            for (int i = 0; i < 4; ++i)
                af[h][i] = *(const bf16x8*)(ldsA + h * 4096 + (wm + i * 16 + l16) * 32 + quad * 8);
#pragma unroll
            for (int j = 0; j < 2; ++j)
                bfr[h][j] = *(const bf16x8*)(ldsB + h * 2048 + (wn + j * 16 + l16) * 32 + quad * 8);
        }
#pragma unroll
        for (int h = 0; h < 2; ++h)
#pragma unroll
            for (int i = 0; i < 4; ++i)
#pragma unroll
                for (int j = 0; j < 2; ++j)
                    acc[i][j] = __builtin_amdgcn_mfma_f32_16x16x32_bf16(af[h][i], bfr[h][j], acc[i][j], 0, 0, 0);
        __syncthreads();
    }

    float* ldsInv = (float*)lds;
    if (tid < 128) ldsInv[tid] = 1.0f / sums[b * S_LEN + m0 + tid];
    __syncthreads();

    float* outb = wout + (size_t)b * S_LEN * DQ;
#pragma unroll
    for (int i = 0; i < 4; ++i) {
#pragma unroll
        for (int r = 0; r < 4; ++r) {
            int lm = wm + i * 16 + quad * 4 + r;
            float inv = ldsInv[lm];
#pragma unroll
            for (int j = 0; j < 2; ++j) {
                int gn = n0 + wn + j * 16 + l16;
                outb[(size_t)(m0 + lm) * DQ + gn] = acc[i][j][r] * inv;
            }
        }
    }

    const u16* Psl = Pb + (size_t)(b * S_LEN + m0) * S_LEN + bx * 256;
    float* Pro = probs + ((size_t)b * S_LEN + m0) * S_LEN + bx * 256;
#pragma unroll
    for (int it = 0; it < 16; ++it) {
        int idx = it * 256 + tid;
        int r  = idx >> 5;
        int cc = (idx & 31) << 3;
        float inv = ldsInv[r];
        bf16x8 vv = *(const bf16x8*)(Psl + (size_t)r * S_LEN + cc);
        f32x4 o0, o1;
        o0.x = bf2f((u16)vv[0]) * inv;
        o0.y = bf2f((u16)vv[1]) * inv;
        o0.z = bf2f((u16)vv[2]) * inv;
        o0.w = bf2f((u16)vv[3]) * inv;
        o1.x = bf2f((u16)vv[4]) * inv;
        o1.y = bf2f((u16)vv[5]) * inv;
        o1.z = bf2f((u16)vv[6]) * inv;
        o1.w = bf2f((u16)vv[7]) * inv;
        float* dst = Pro + (size_t)r * S_LEN + cc;
        *(f32x4*)(dst) = o0;
        *(f32x4*)(dst + 4) = o1;
    }
}

extern "C" void kernel_launch(void* const* d_in, const int* in_sizes, int n_in,
                              void* d_out, int out_size, void* d_ws, size_t ws_size,
                              hipStream_t stream) {
    const float* x  = (const float*)d_in[0];
    const float* Wq = (const float*)d_in[1];
    const float* bq = (const float*)d_in[2];
    const float* Wk = (const float*)d_in[3];
    const float* bk = (const float*)d_in[4];
    const float* Wv = (const float*)d_in[5];
    const float* bv = (const float*)d_in[6];

    char* ws = (char*)d_ws;
    u16* xb  = (u16*)(ws);                 // x bf16        [8192][512]   8.39 MB
    u16* Wb  = (u16*)(ws + 8388608);       // Wq,Wk,Wv bf16 3x[512][512]  1.57 MB
    u16* Qb  = (u16*)(ws + 9961472);       // Q bf16        [8192][512]
    u16* Kb  = (u16*)(ws + 18350080);      // K bf16        [8192][512]
    u16* VTb = (u16*)(ws + 35127296);      // V^T bf16      [4][512][2048]
    u16* Pb  = (u16*)(ws + 43515904);      // e bf16 (unnormalized) [8192][2048]  33.6 MB
    float* sums = (float*)(ws + 77070336); // [8192] fp32 row sums (atomic)
    float* probs = (float*)d_out;                        // [4][2048][2048]
    float* wout  = (float*)d_out + 16777216;             // [4][2048][512]

    k_cvt_all<<<4872, 256, 0, stream>>>(x, Wq, Wk, Wv, xb, Wb, sums);
    k_proj<<<192, 512, 0, stream>>>(xb, Wb, bq, bk, bv, Qb, VTb);
    k_scores<<<256, 512, 0, stream>>>(Qb, Kb, Pb, sums);
    k_pv<<<512, 256, 0, stream>>>(Pb, VTb, sums, probs, wout);
}

// Round 5
// 187.194 us; speedup vs baseline: 1.1085x; 1.0309x over previous
//
#include <hip/hip_runtime.h>
#include <hip/hip_bf16.h>

typedef unsigned short u16;
typedef short bf16x8 __attribute__((ext_vector_type(8)));
typedef float f32x4 __attribute__((ext_vector_type(4)));

#define S_LEN 2048
#define DQ 512
#define NBATCH 4

__device__ __forceinline__ u16 f2bf(float f) {
    __hip_bfloat16 h = __float2bfloat16(f);
    return *reinterpret_cast<u16*>(&h);
}
__device__ __forceinline__ float bf2f(u16 u) {
    unsigned v = ((unsigned)u) << 16;
    union { unsigned u; float f; } c; c.u = v; return c.f;
}

__device__ __forceinline__ void async16(const u16* g, u16* l) {
    __builtin_amdgcn_global_load_lds(
        (__attribute__((address_space(1))) void*)g,
        (__attribute__((address_space(3))) void*)l, 16, 0, 0);
}

// XCD-chunked bijective swizzle (T1): hardware assigns dispatch id d -> XCD d%8.
__device__ __forceinline__ int xcd_swz(int bid, int chunk) {
    return (bid & 7) * chunk + (bid >> 3);
}

// -------- fp32 -> bf16 convert: x + Wq + Wk + Wv; tail blocks zero the sums buffer --------
__global__ __launch_bounds__(256) void k_cvt_all(const float* __restrict__ x,
                                                 const float* __restrict__ wq,
                                                 const float* __restrict__ wk,
                                                 const float* __restrict__ wv,
                                                 u16* __restrict__ xb, u16* __restrict__ wb,
                                                 float* __restrict__ sums) {
    int bid = blockIdx.x;
    if (bid >= 4864) {  // 8 blocks zero sums[8192]
        int i = (bid - 4864) * 256 + threadIdx.x;
        *(f32x4*)(sums + (size_t)i * 4) = (f32x4)0.0f;
        return;
    }
    const float* src;
    u16* dst;
    int i;
    if (bid < 4096)      { src = x;  dst = xb;          i = bid * 256 + threadIdx.x; }
    else if (bid < 4352) { src = wq; dst = wb;          i = (bid - 4096) * 256 + threadIdx.x; }
    else if (bid < 4608) { src = wk; dst = wb + 262144; i = (bid - 4352) * 256 + threadIdx.x; }
    else                 { src = wv; dst = wb + 524288; i = (bid - 4608) * 256 + threadIdx.x; }
    f32x4 v = *(const f32x4*)(src + (size_t)i * 4);
    ushort4 o;
    o.x = f2bf(v.x); o.y = f2bf(v.y); o.z = f2bf(v.z); o.w = f2bf(v.w);
    *(ushort4*)(dst + (size_t)i * 4) = o;
}

// ================= 256x256 double-buffered GEMM core (BK=64, 8 waves) =================
// LDS layout per matrix buffer: [256 rows][64 cols] bf16, 128 B/row = 8 chunks of 16 B.
// XOR swizzle (T2/st-16x32): physical chunk = logical chunk ^ (row & 7).
// Staged via global_load_lds with LINEAR LDS dest + pre-swizzled GLOBAL source (rule 21).
__device__ __forceinline__ void stage_unit(const u16* __restrict__ G, u16* buf,
                                           int kcol, int h, int tid) {
#pragma unroll
    for (int q = 0; q < 2; ++q) {
        int c   = q * 512 + tid;          // 16B chunk id 0..1023 within half-tile
        int r   = c >> 3;                 // row 0..127 within half
        int p   = c & 7;                  // physical chunk within row
        int lch = p ^ (r & 7);            // logical (global) chunk
        async16(G + (size_t)(h * 128 + r) * DQ + kcol + lch * 8,
                buf + h * 8192 + c * 8);  // linear dest: wave-uniform base + lane*16B
    }
}

// A,B: row-major panels [256][512] (row stride DQ). C = A * B^T on 256x256 tile.
__device__ __forceinline__ void gemm256(const u16* __restrict__ A, const u16* __restrict__ B,
                                        u16* ldsA, u16* ldsB, f32x4 acc[8][4], int tid) {
    const int lane = tid & 63;
    const int w    = tid >> 6;
    const int wr   = w >> 2;
    const int wc   = w & 3;
    const int l16  = lane & 15;
    const int quad = lane >> 4;
    const int p0   = quad ^ (l16 & 7);
    const int a0   = (wr * 128 + l16) * 64 + p0 * 8;
    const int a1   = (wr * 128 + l16) * 64 + (p0 ^ 4) * 8;
    const int b0   = (wc * 64 + l16) * 64 + p0 * 8;
    const int b1   = (wc * 64 + l16) * 64 + (p0 ^ 4) * 8;

    stage_unit(A, ldsA, 0, 0, tid);
    stage_unit(A, ldsA, 0, 1, tid);
    stage_unit(B, ldsB, 0, 0, tid);
    stage_unit(B, ldsB, 0, 1, tid);
    __syncthreads();

    for (int kt = 0; kt < 8; ++kt) {
        const u16* rdA = ldsA + (kt & 1) * 16384;
        const u16* rdB = ldsB + (kt & 1) * 16384;
        u16* wrA = ldsA + ((kt + 1) & 1) * 16384;
        u16* wrB = ldsB + ((kt + 1) & 1) * 16384;
        const int  kc = (kt + 1) * 64;
        const bool pf = kt < 7;
        bf16x8 a[4][2], bbf[2][2];

        if (pf) stage_unit(A, wrA, kc, 0, tid);
#pragma unroll
        for (int i = 0; i < 4; ++i) {
            a[i][0] = *(const bf16x8*)(rdA + a0 + i * 1024);
            a[i][1] = *(const bf16x8*)(rdA + a1 + i * 1024);
        }
#pragma unroll
        for (int j = 0; j < 2; ++j) {
            bbf[j][0] = *(const bf16x8*)(rdB + b0 + j * 1024);
            bbf[j][1] = *(const bf16x8*)(rdB + b1 + j * 1024);
        }
        __builtin_amdgcn_s_setprio(1);
#pragma unroll
        for (int i = 0; i < 4; ++i)
#pragma unroll
            for (int j = 0; j < 2; ++j) {
                acc[i][j] = __builtin_amdgcn_mfma_f32_16x16x32_bf16(a[i][0], bbf[j][0], acc[i][j], 0, 0, 0);
                acc[i][j] = __builtin_amdgcn_mfma_f32_16x16x32_bf16(a[i][1], bbf[j][1], acc[i][j], 0, 0, 0);
            }
        __builtin_amdgcn_s_setprio(0);

        if (pf) stage_unit(A, wrA, kc, 1, tid);
#pragma unroll
        for (int j = 0; j < 2; ++j) {
            bbf[j][0] = *(const bf16x8*)(rdB + b0 + (2 + j) * 1024);
            bbf[j][1] = *(const bf16x8*)(rdB + b1 + (2 + j) * 1024);
        }
        __builtin_amdgcn_s_setprio(1);
#pragma unroll
        for (int i = 0; i < 4; ++i)
#pragma unroll
            for (int j = 0; j < 2; ++j) {
                acc[i][2 + j] = __builtin_amdgcn_mfma_f32_16x16x32_bf16(a[i][0], bbf[j][0], acc[i][2 + j], 0, 0, 0);
                acc[i][2 + j] = __builtin_amdgcn_mfma_f32_16x16x32_bf16(a[i][1], bbf[j][1], acc[i][2 + j], 0, 0, 0);
            }
        __builtin_amdgcn_s_setprio(0);

        if (pf) stage_unit(B, wrB, kc, 0, tid);
#pragma unroll
        for (int i = 0; i < 4; ++i) {
            a[i][0] = *(const bf16x8*)(rdA + a0 + (4 + i) * 1024);
            a[i][1] = *(const bf16x8*)(rdA + a1 + (4 + i) * 1024);
        }
        __builtin_amdgcn_s_setprio(1);
#pragma unroll
        for (int i = 0; i < 4; ++i)
#pragma unroll
            for (int j = 0; j < 2; ++j) {
                acc[4 + i][2 + j] = __builtin_amdgcn_mfma_f32_16x16x32_bf16(a[i][0], bbf[j][0], acc[4 + i][2 + j], 0, 0, 0);
                acc[4 + i][2 + j] = __builtin_amdgcn_mfma_f32_16x16x32_bf16(a[i][1], bbf[j][1], acc[4 + i][2 + j], 0, 0, 0);
            }
        __builtin_amdgcn_s_setprio(0);

        if (pf) stage_unit(B, wrB, kc, 1, tid);
#pragma unroll
        for (int j = 0; j < 2; ++j) {
            bbf[j][0] = *(const bf16x8*)(rdB + b0 + j * 1024);
            bbf[j][1] = *(const bf16x8*)(rdB + b1 + j * 1024);
        }
        __builtin_amdgcn_s_setprio(1);
#pragma unroll
        for (int i = 0; i < 4; ++i)
#pragma unroll
            for (int j = 0; j < 2; ++j) {
                acc[4 + i][j] = __builtin_amdgcn_mfma_f32_16x16x32_bf16(a[i][0], bbf[j][0], acc[4 + i][j], 0, 0, 0);
                acc[4 + i][j] = __builtin_amdgcn_mfma_f32_16x16x32_bf16(a[i][1], bbf[j][1], acc[4 + i][j], 0, 0, 0);
            }
        __builtin_amdgcn_s_setprio(0);

        __syncthreads();
    }
}

// -------- projection: z in {Q,K,V}; 256x256 tiles; nwg = 192 = (z=3)x(by=32)x(bx=2) --------
__global__ __launch_bounds__(512, 2) void k_proj(const u16* __restrict__ xb, const u16* __restrict__ Wb,
                                                 const float* __restrict__ bq, const float* __restrict__ bk,
                                                 const float* __restrict__ bv, u16* __restrict__ out,
                                                 u16* __restrict__ VT) {
    __shared__ __align__(16) u16 lds[65536];   // 128 KiB: A 2x16384 | B 2x16384
    const int l  = xcd_swz(blockIdx.x, 24);
    const int bx = l & 1;
    const int by = (l >> 1) & 31;
    const int z  = l >> 6;
    const int m0 = by * 256, n0 = bx * 256;
    const u16* A = xb + (size_t)m0 * DQ;
    const u16* B = Wb + (size_t)z * DQ * DQ + (size_t)n0 * DQ;
    const float* bias = (z == 0) ? bq : (z == 1) ? bk : bv;

    f32x4 acc[8][4];
#pragma unroll
    for (int i = 0; i < 8; ++i)
#pragma unroll
        for (int j = 0; j < 4; ++j) acc[i][j] = (f32x4)0.0f;

    const int tid = threadIdx.x;
    gemm256(A, B, lds, lds + 32768, acc, tid);

    const int lane = tid & 63, w = tid >> 6;
    const int wr = w >> 2, wc = w & 3;
    const int l16 = lane & 15, quad = lane >> 4;

    if (z < 2) {
        u16* outz = out + (size_t)z * 8192 * DQ;
#pragma unroll
        for (int j = 0; j < 4; ++j) {
            int gn = n0 + wc * 64 + j * 16 + l16;
            float bv_ = bias[gn];
#pragma unroll
            for (int i = 0; i < 8; ++i)
#pragma unroll
                for (int r = 0; r < 4; ++r) {
                    int gm = m0 + wr * 128 + i * 16 + quad * 4 + r;
                    outz[(size_t)gm * DQ + gn] = f2bf(acc[i][j][r] + bv_);
                }
        }
    } else {
        const int bb_ = m0 >> 11;
        u16* VTb_ = VT + (size_t)bb_ * DQ * S_LEN;
#pragma unroll
        for (int j = 0; j < 4; ++j) {
            int gn = n0 + wc * 64 + j * 16 + l16;
            float bv_ = bias[gn];
#pragma unroll
            for (int i = 0; i < 8; ++i) {
                int t0 = (m0 & 2047) + wr * 128 + i * 16 + quad * 4;
                ushort4 o;
                o.x = f2bf(acc[i][j][0] + bv_);
                o.y = f2bf(acc[i][j][1] + bv_);
                o.z = f2bf(acc[i][j][2] + bv_);
                o.w = f2bf(acc[i][j][3] + bv_);
                *(ushort4*)(VTb_ + (size_t)gn * S_LEN + t0) = o;
            }
        }
    }
}

// -------- scores: 256x256 tiles; e=exp(QK^T*scale)->bf16 Pb + atomic row sums --------
__global__ __launch_bounds__(512, 2) void k_scores(const u16* __restrict__ Qb, const u16* __restrict__ Kb,
                                                   u16* __restrict__ Pb, float* __restrict__ sums) {
    __shared__ __align__(16) u16 lds[65536];
    const int l  = xcd_swz(blockIdx.x, 32);
    const int bx = l & 7;
    const int by = (l >> 3) & 7;
    const int b  = l >> 6;
    const int m0 = by * 256, n0 = bx * 256;
    const u16* A = Qb + ((size_t)b * S_LEN + m0) * DQ;
    const u16* B = Kb + ((size_t)b * S_LEN + n0) * DQ;

    f32x4 acc[8][4];
#pragma unroll
    for (int i = 0; i < 8; ++i)
#pragma unroll
        for (int j = 0; j < 4; ++j) acc[i][j] = (f32x4)0.0f;

    const int tid = threadIdx.x;
    gemm256(A, B, lds, lds + 32768, acc, tid);

    const float scale = 0.044194173824159216f; // 1/sqrt(512)
    const int lane = tid & 63, w = tid >> 6;
    const int wr = w >> 2, wc = w & 3;
    const int l16 = lane & 15, quad = lane >> 4;
    u16* prow = Pb + (size_t)(b * S_LEN + m0) * S_LEN;

    float psum[8][4];
#pragma unroll
    for (int i = 0; i < 8; ++i)
#pragma unroll
        for (int r = 0; r < 4; ++r) psum[i][r] = 0.0f;

#pragma unroll
    for (int i = 0; i < 8; ++i)
#pragma unroll
        for (int j = 0; j < 4; ++j)
#pragma unroll
            for (int r = 0; r < 4; ++r) {
                int gm = wr * 128 + i * 16 + quad * 4 + r;
                int gn = n0 + wc * 64 + j * 16 + l16;
                float e = __expf(acc[i][j][r] * scale);
                u16 pbv = f2bf(e);
                prow[(size_t)gm * S_LEN + gn] = pbv;
                psum[i][r] += bf2f(pbv);
            }

    float* sums_row = sums + b * S_LEN + m0 + wr * 128;
#pragma unroll
    for (int i = 0; i < 8; ++i)
#pragma unroll
        for (int r = 0; r < 4; ++r) {
            float v = psum[i][r];
            v += __shfl_xor(v, 1);
            v += __shfl_xor(v, 2);
            v += __shfl_xor(v, 4);
            v += __shfl_xor(v, 8);
            if (l16 == 0) atomicAdd(&sums_row[i * 16 + quad * 4 + r], v);
        }
}

// ======== k_pv: 128x128 tile, 8 waves, BK=64, double-buffered swizzled LDS ========
// A = Pb panel [128][2048], B = VT panel [128][2048] (both row stride S_LEN).
// Per K-tile: A/B halves = 64 rows x 64 cols, 1 async16/thread per half.
__device__ __forceinline__ void stage_pv(const u16* __restrict__ G, u16* buf,
                                         int kcol, int h, int tid) {
    int c   = tid;                 // 16B chunk 0..511 within half (64 rows x 8 chunks)
    int r   = c >> 3;              // row 0..63
    int p   = c & 7;               // physical chunk
    int lch = p ^ (r & 7);         // logical chunk (pre-swizzled source)
    async16(G + (size_t)(h * 64 + r) * S_LEN + kcol + lch * 8,
            buf + h * 4096 + c * 8);
}

// nwg = 256 = (b=4)x(by=16)x(bx=4); chunk 32/XCD. Block bx also writes the
// normalized fp32 probs for its 128x512 col-slice post-loop (global Pb, L2-hot).
__global__ __launch_bounds__(512, 2) void k_pv(const u16* __restrict__ Pb, const u16* __restrict__ VT,
                                               const float* __restrict__ sums,
                                               float* __restrict__ probs,
                                               float* __restrict__ wout) {
    __shared__ __align__(16) u16 lds[32768];   // 64 KiB: A 2x8192 | B 2x8192
    u16* ldsA = lds;
    u16* ldsB = lds + 16384;
    const int l  = xcd_swz(blockIdx.x, 32);
    const int bx = l & 3;
    const int by = (l >> 2) & 15;
    const int b  = l >> 6;
    const int m0 = by * 128, n0 = bx * 128;
    const u16* A = Pb + (size_t)(b * S_LEN + m0) * S_LEN;
    const u16* B = VT + (size_t)b * DQ * S_LEN + (size_t)n0 * S_LEN;

    const int tid  = threadIdx.x;
    const int lane = tid & 63;
    const int w    = tid >> 6;
    const int wr   = w >> 2;       // 0..1 -> rows wr*64..+63
    const int wc   = w & 3;        // 0..3 -> cols wc*32..+31
    const int l16  = lane & 15;
    const int quad = lane >> 4;
    const int p0   = quad ^ (l16 & 7);
    const int a0   = (wr * 64 + l16) * 64 + p0 * 8;
    const int a1   = (wr * 64 + l16) * 64 + (p0 ^ 4) * 8;
    const int b0   = (wc * 32 + l16) * 64 + p0 * 8;
    const int b1   = (wc * 32 + l16) * 64 + (p0 ^ 4) * 8;

    f32x4 acc[4][2];
#pragma unroll
    for (int i = 0; i < 4; ++i)
#pragma unroll
        for (int j = 0; j < 2; ++j) acc[i][j] = (f32x4)0.0f;

    stage_pv(A, ldsA, 0, 0, tid);
    stage_pv(A, ldsA, 0, 1, tid);
    stage_pv(B, ldsB, 0, 0, tid);
    stage_pv(B, ldsB, 0, 1, tid);
    __syncthreads();

    for (int kt = 0; kt < 32; ++kt) {
        const u16* rdA = ldsA + (kt & 1) * 8192;
        const u16* rdB = ldsB + (kt & 1) * 8192;
        u16* wrA = ldsA + ((kt + 1) & 1) * 8192;
        u16* wrB = ldsB + ((kt + 1) & 1) * 8192;
        const int  kc = (kt + 1) * 64;
        const bool pf = kt < 31;
        bf16x8 a[4][2], bbf[2];

        // G0: prefetch A(kt+1); read all A frags + B n0; MFMA m0-3 x n0
        if (pf) { stage_pv(A, wrA, kc, 0, tid); stage_pv(A, wrA, kc, 1, tid); }
#pragma unroll
        for (int i = 0; i < 4; ++i) {
            a[i][0] = *(const bf16x8*)(rdA + a0 + i * 1024);
            a[i][1] = *(const bf16x8*)(rdA + a1 + i * 1024);
        }
        bbf[0] = *(const bf16x8*)(rdB + b0);
        bbf[1] = *(const bf16x8*)(rdB + b1);
        __builtin_amdgcn_s_setprio(1);
#pragma unroll
        for (int i = 0; i < 4; ++i) {
            acc[i][0] = __builtin_amdgcn_mfma_f32_16x16x32_bf16(a[i][0], bbf[0], acc[i][0], 0, 0, 0);
            acc[i][0] = __builtin_amdgcn_mfma_f32_16x16x32_bf16(a[i][1], bbf[1], acc[i][0], 0, 0, 0);
        }
        __builtin_amdgcn_s_setprio(0);

        // G1: prefetch B(kt+1); read B n1; MFMA m0-3 x n1
        if (pf) { stage_pv(B, wrB, kc, 0, tid); stage_pv(B, wrB, kc, 1, tid); }
        bbf[0] = *(const bf16x8*)(rdB + b0 + 1024);
        bbf[1] = *(const bf16x8*)(rdB + b1 + 1024);
        __builtin_amdgcn_s_setprio(1);
#pragma unroll
        for (int i = 0; i < 4; ++i) {
            acc[i][1] = __builtin_amdgcn_mfma_f32_16x16x32_bf16(a[i][0], bbf[0], acc[i][1], 0, 0, 0);
            acc[i][1] = __builtin_amdgcn_mfma_f32_16x16x32_bf16(a[i][1], bbf[1], acc[i][1], 0, 0, 0);
        }
        __builtin_amdgcn_s_setprio(0);

        __syncthreads();
    }

    // inv table (128 rows), then wout epilogue + probs slice
    float* ldsInv = (float*)lds;
    if (tid < 128) ldsInv[tid] = 1.0f / sums[b * S_LEN + m0 + tid];
    __syncthreads();

    float* outb = wout + (size_t)b * S_LEN * DQ;
#pragma unroll
    for (int i = 0; i < 4; ++i) {
#pragma unroll
        for (int r = 0; r < 4; ++r) {
            int lm = wr * 64 + i * 16 + quad * 4 + r;
            float inv = ldsInv[lm];
#pragma unroll
            for (int j = 0; j < 2; ++j) {
                int gn = n0 + wc * 32 + j * 16 + l16;
                outb[(size_t)(m0 + lm) * DQ + gn] = acc[i][j][r] * inv;
            }
        }
    }

    // normalized probs for this block's 128x512 col-slice, from global Pb (L2)
    const u16* Psl = Pb + (size_t)(b * S_LEN + m0) * S_LEN + bx * 512;
    float* Pro = probs + ((size_t)b * S_LEN + m0) * S_LEN + bx * 512;
#pragma unroll
    for (int it = 0; it < 16; ++it) {
        int idx = it * 512 + tid;       // 8192 chunks of 8 elems
        int r  = idx >> 6;              // row 0..127
        int cc = (idx & 63) << 3;       // col 0..511 step 8
        float inv = ldsInv[r];
        bf16x8 vv = *(const bf16x8*)(Psl + (size_t)r * S_LEN + cc);
        f32x4 o0, o1;
        o0.x = bf2f((u16)vv[0]) * inv;
        o0.y = bf2f((u16)vv[1]) * inv;
        o0.z = bf2f((u16)vv[2]) * inv;
        o0.w = bf2f((u16)vv[3]) * inv;
        o1.x = bf2f((u16)vv[4]) * inv;
        o1.y = bf2f((u16)vv[5]) * inv;
        o1.z = bf2f((u16)vv[6]) * inv;
        o1.w = bf2f((u16)vv[7]) * inv;
        float* dst = Pro + (size_t)r * S_LEN + cc;
        *(f32x4*)(dst) = o0;
        *(f32x4*)(dst + 4) = o1;
    }
}

extern "C" void kernel_launch(void* const* d_in, const int* in_sizes, int n_in,
                              void* d_out, int out_size, void* d_ws, size_t ws_size,
                              hipStream_t stream) {
    const float* x  = (const float*)d_in[0];
    const float* Wq = (const float*)d_in[1];
    const float* bq = (const float*)d_in[2];
    const float* Wk = (const float*)d_in[3];
    const float* bk = (const float*)d_in[4];
    const float* Wv = (const float*)d_in[5];
    const float* bv = (const float*)d_in[6];

    char* ws = (char*)d_ws;
    u16* xb  = (u16*)(ws);                 // x bf16        [8192][512]   8.39 MB
    u16* Wb  = (u16*)(ws + 8388608);       // Wq,Wk,Wv bf16 3x[512][512]  1.57 MB
    u16* Qb  = (u16*)(ws + 9961472);       // Q bf16        [8192][512]
    u16* Kb  = (u16*)(ws + 18350080);      // K bf16        [8192][512]
    u16* VTb = (u16*)(ws + 35127296);      // V^T bf16      [4][512][2048]
    u16* Pb  = (u16*)(ws + 43515904);      // e bf16 (unnormalized) [8192][2048]  33.6 MB
    float* sums = (float*)(ws + 77070336); // [8192] fp32 row sums (atomic)
    float* probs = (float*)d_out;                        // [4][2048][2048]
    float* wout  = (float*)d_out + 16777216;             // [4][2048][512]

    k_cvt_all<<<4872, 256, 0, stream>>>(x, Wq, Wk, Wv, xb, Wb, sums);
    k_proj<<<192, 512, 0, stream>>>(xb, Wb, bq, bk, bv, Qb, VTb);
    k_scores<<<256, 512, 0, stream>>>(Qb, Kb, Pb, sums);
    k_pv<<<256, 512, 0, stream>>>(Pb, VTb, sums, probs, wout);
}

// Round 6
// 182.186 us; speedup vs baseline: 1.1389x; 1.0275x over previous
//
#include <hip/hip_runtime.h>
#include <hip/hip_bf16.h>

typedef unsigned short u16;
typedef short bf16x8 __attribute__((ext_vector_type(8)));
typedef float f32x4 __attribute__((ext_vector_type(4)));

#define S_LEN 2048
#define DQ 512
#define NBATCH 4

__device__ __forceinline__ u16 f2bf(float f) {
    __hip_bfloat16 h = __float2bfloat16(f);
    return *reinterpret_cast<u16*>(&h);
}
__device__ __forceinline__ float bf2f(u16 u) {
    unsigned v = ((unsigned)u) << 16;
    union { unsigned u; float f; } c; c.u = v; return c.f;
}

__device__ __forceinline__ void async16(const u16* g, u16* l) {
    __builtin_amdgcn_global_load_lds(
        (__attribute__((address_space(1))) void*)g,
        (__attribute__((address_space(3))) void*)l, 16, 0, 0);
}

// XCD-chunked bijective swizzle (T1): hardware assigns dispatch id d -> XCD d%8.
__device__ __forceinline__ int xcd_swz(int bid, int chunk) {
    return (bid & 7) * chunk + (bid >> 3);
}

// -------- fp32 -> bf16 convert: x + Wq + Wk + Wv; tail blocks zero the sums buffer --------
__global__ __launch_bounds__(256) void k_cvt_all(const float* __restrict__ x,
                                                 const float* __restrict__ wq,
                                                 const float* __restrict__ wk,
                                                 const float* __restrict__ wv,
                                                 u16* __restrict__ xb, u16* __restrict__ wb,
                                                 float* __restrict__ sums) {
    int bid = blockIdx.x;
    if (bid >= 4864) {  // 8 blocks zero sums[8192]
        int i = (bid - 4864) * 256 + threadIdx.x;
        *(f32x4*)(sums + (size_t)i * 4) = (f32x4)0.0f;
        return;
    }
    const float* src;
    u16* dst;
    int i;
    if (bid < 4096)      { src = x;  dst = xb;          i = bid * 256 + threadIdx.x; }
    else if (bid < 4352) { src = wq; dst = wb;          i = (bid - 4096) * 256 + threadIdx.x; }
    else if (bid < 4608) { src = wk; dst = wb + 262144; i = (bid - 4352) * 256 + threadIdx.x; }
    else                 { src = wv; dst = wb + 524288; i = (bid - 4608) * 256 + threadIdx.x; }
    f32x4 v = *(const f32x4*)(src + (size_t)i * 4);
    ushort4 o;
    o.x = f2bf(v.x); o.y = f2bf(v.y); o.z = f2bf(v.z); o.w = f2bf(v.w);
    *(ushort4*)(dst + (size_t)i * 4) = o;
}

// ================= 256x256 double-buffered GEMM core (BK=64, 8 waves) =================
// LDS layout per matrix buffer: [256 rows][64 cols] bf16, 128 B/row = 8 chunks of 16 B.
// XOR swizzle (T2/st-16x32): physical chunk = logical chunk ^ (row & 7).
// Staged via global_load_lds with LINEAR LDS dest + pre-swizzled GLOBAL source (rule 21).
__device__ __forceinline__ void stage_unit(const u16* __restrict__ G, u16* buf,
                                           int kcol, int h, int tid) {
#pragma unroll
    for (int q = 0; q < 2; ++q) {
        int c   = q * 512 + tid;          // 16B chunk id 0..1023 within half-tile
        int r   = c >> 3;                 // row 0..127 within half
        int p   = c & 7;                  // physical chunk within row
        int lch = p ^ (r & 7);            // logical (global) chunk
        async16(G + (size_t)(h * 128 + r) * DQ + kcol + lch * 8,
                buf + h * 8192 + c * 8);  // linear dest: wave-uniform base + lane*16B
    }
}

// A,B: row-major panels [256][512] (row stride DQ). C = A * B^T on 256x256 tile.
// All 4 next-tile stages issued in the first two MFMA groups -> later loads get
// ~2-3 groups (~300 cyc) of compute cover before the tile-end drain.
__device__ __forceinline__ void gemm256(const u16* __restrict__ A, const u16* __restrict__ B,
                                        u16* ldsA, u16* ldsB, f32x4 acc[8][4], int tid) {
    const int lane = tid & 63;
    const int w    = tid >> 6;
    const int wr   = w >> 2;
    const int wc   = w & 3;
    const int l16  = lane & 15;
    const int quad = lane >> 4;
    const int p0   = quad ^ (l16 & 7);
    const int a0   = (wr * 128 + l16) * 64 + p0 * 8;
    const int a1   = (wr * 128 + l16) * 64 + (p0 ^ 4) * 8;
    const int b0   = (wc * 64 + l16) * 64 + p0 * 8;
    const int b1   = (wc * 64 + l16) * 64 + (p0 ^ 4) * 8;

    stage_unit(A, ldsA, 0, 0, tid);
    stage_unit(A, ldsA, 0, 1, tid);
    stage_unit(B, ldsB, 0, 0, tid);
    stage_unit(B, ldsB, 0, 1, tid);
    __syncthreads();

    for (int kt = 0; kt < 8; ++kt) {
        const u16* rdA = ldsA + (kt & 1) * 16384;
        const u16* rdB = ldsB + (kt & 1) * 16384;
        u16* wrA = ldsA + ((kt + 1) & 1) * 16384;
        u16* wrB = ldsB + ((kt + 1) & 1) * 16384;
        const int  kc = (kt + 1) * 64;
        const bool pf = kt < 7;
        bf16x8 a[4][2], bbf[2][2];

        // ---- G0: stage A-half0+half1(kt+1); read A m0-3 + B n0-1; MFMA ----
        if (pf) { stage_unit(A, wrA, kc, 0, tid); stage_unit(A, wrA, kc, 1, tid); }
#pragma unroll
        for (int i = 0; i < 4; ++i) {
            a[i][0] = *(const bf16x8*)(rdA + a0 + i * 1024);
            a[i][1] = *(const bf16x8*)(rdA + a1 + i * 1024);
        }
#pragma unroll
        for (int j = 0; j < 2; ++j) {
            bbf[j][0] = *(const bf16x8*)(rdB + b0 + j * 1024);
            bbf[j][1] = *(const bf16x8*)(rdB + b1 + j * 1024);
        }
        __builtin_amdgcn_s_setprio(1);
#pragma unroll
        for (int i = 0; i < 4; ++i)
#pragma unroll
            for (int j = 0; j < 2; ++j) {
                acc[i][j] = __builtin_amdgcn_mfma_f32_16x16x32_bf16(a[i][0], bbf[j][0], acc[i][j], 0, 0, 0);
                acc[i][j] = __builtin_amdgcn_mfma_f32_16x16x32_bf16(a[i][1], bbf[j][1], acc[i][j], 0, 0, 0);
            }
        __builtin_amdgcn_s_setprio(0);

        // ---- G1: stage B-half0+half1(kt+1); read B n2-3; MFMA m0-3 x n2-3 ----
        if (pf) { stage_unit(B, wrB, kc, 0, tid); stage_unit(B, wrB, kc, 1, tid); }
#pragma unroll
        for (int j = 0; j < 2; ++j) {
            bbf[j][0] = *(const bf16x8*)(rdB + b0 + (2 + j) * 1024);
            bbf[j][1] = *(const bf16x8*)(rdB + b1 + (2 + j) * 1024);
        }
        __builtin_amdgcn_s_setprio(1);
#pragma unroll
        for (int i = 0; i < 4; ++i)
#pragma unroll
            for (int j = 0; j < 2; ++j) {
                acc[i][2 + j] = __builtin_amdgcn_mfma_f32_16x16x32_bf16(a[i][0], bbf[j][0], acc[i][2 + j], 0, 0, 0);
                acc[i][2 + j] = __builtin_amdgcn_mfma_f32_16x16x32_bf16(a[i][1], bbf[j][1], acc[i][2 + j], 0, 0, 0);
            }
        __builtin_amdgcn_s_setprio(0);

        // ---- G2: read A m4-7; MFMA m4-7 x n2-3 ----
#pragma unroll
        for (int i = 0; i < 4; ++i) {
            a[i][0] = *(const bf16x8*)(rdA + a0 + (4 + i) * 1024);
            a[i][1] = *(const bf16x8*)(rdA + a1 + (4 + i) * 1024);
        }
        __builtin_amdgcn_s_setprio(1);
#pragma unroll
        for (int i = 0; i < 4; ++i)
#pragma unroll
            for (int j = 0; j < 2; ++j) {
                acc[4 + i][2 + j] = __builtin_amdgcn_mfma_f32_16x16x32_bf16(a[i][0], bbf[j][0], acc[4 + i][2 + j], 0, 0, 0);
                acc[4 + i][2 + j] = __builtin_amdgcn_mfma_f32_16x16x32_bf16(a[i][1], bbf[j][1], acc[4 + i][2 + j], 0, 0, 0);
            }
        __builtin_amdgcn_s_setprio(0);

        // ---- G3: read B n0-1 again; MFMA m4-7 x n0-1 ----
#pragma unroll
        for (int j = 0; j < 2; ++j) {
            bbf[j][0] = *(const bf16x8*)(rdB + b0 + j * 1024);
            bbf[j][1] = *(const bf16x8*)(rdB + b1 + j * 1024);
        }
        __builtin_amdgcn_s_setprio(1);
#pragma unroll
        for (int i = 0; i < 4; ++i)
#pragma unroll
            for (int j = 0; j < 2; ++j) {
                acc[4 + i][j] = __builtin_amdgcn_mfma_f32_16x16x32_bf16(a[i][0], bbf[j][0], acc[4 + i][j], 0, 0, 0);
                acc[4 + i][j] = __builtin_amdgcn_mfma_f32_16x16x32_bf16(a[i][1], bbf[j][1], acc[4 + i][j], 0, 0, 0);
            }
        __builtin_amdgcn_s_setprio(0);

        __syncthreads();
    }
}

// -------- projection: z in {Q,K,V}; 256x256 tiles; nwg = 192 = (z=3)x(by=32)x(bx=2) --------
__global__ __launch_bounds__(512, 2) void k_proj(const u16* __restrict__ xb, const u16* __restrict__ Wb,
                                                 const float* __restrict__ bq, const float* __restrict__ bk,
                                                 const float* __restrict__ bv, u16* __restrict__ out,
                                                 u16* __restrict__ VT) {
    __shared__ __align__(16) u16 lds[65536];   // 128 KiB: A 2x16384 | B 2x16384
    const int l  = xcd_swz(blockIdx.x, 24);
    const int bx = l & 1;
    const int by = (l >> 1) & 31;
    const int z  = l >> 6;
    const int m0 = by * 256, n0 = bx * 256;
    const u16* A = xb + (size_t)m0 * DQ;
    const u16* B = Wb + (size_t)z * DQ * DQ + (size_t)n0 * DQ;
    const float* bias = (z == 0) ? bq : (z == 1) ? bk : bv;

    f32x4 acc[8][4];
#pragma unroll
    for (int i = 0; i < 8; ++i)
#pragma unroll
        for (int j = 0; j < 4; ++j) acc[i][j] = (f32x4)0.0f;

    const int tid = threadIdx.x;
    gemm256(A, B, lds, lds + 32768, acc, tid);

    const int lane = tid & 63, w = tid >> 6;
    const int wr = w >> 2, wc = w & 3;
    const int l16 = lane & 15, quad = lane >> 4;

    if (z < 2) {
        u16* outz = out + (size_t)z * 8192 * DQ;
#pragma unroll
        for (int j = 0; j < 4; ++j) {
            int gn = n0 + wc * 64 + j * 16 + l16;
            float bv_ = bias[gn];
#pragma unroll
            for (int i = 0; i < 8; ++i)
#pragma unroll
                for (int r = 0; r < 4; ++r) {
                    int gm = m0 + wr * 128 + i * 16 + quad * 4 + r;
                    outz[(size_t)gm * DQ + gn] = f2bf(acc[i][j][r] + bv_);
                }
        }
    } else {
        const int bb_ = m0 >> 11;
        u16* VTb_ = VT + (size_t)bb_ * DQ * S_LEN;
#pragma unroll
        for (int j = 0; j < 4; ++j) {
            int gn = n0 + wc * 64 + j * 16 + l16;
            float bv_ = bias[gn];
#pragma unroll
            for (int i = 0; i < 8; ++i) {
                int t0 = (m0 & 2047) + wr * 128 + i * 16 + quad * 4;
                ushort4 o;
                o.x = f2bf(acc[i][j][0] + bv_);
                o.y = f2bf(acc[i][j][1] + bv_);
                o.z = f2bf(acc[i][j][2] + bv_);
                o.w = f2bf(acc[i][j][3] + bv_);
                *(ushort4*)(VTb_ + (size_t)gn * S_LEN + t0) = o;
            }
        }
    }
}

// -------- scores: 256x256 tiles; e=exp(QK^T*scale)->bf16 Pb + atomic row sums --------
__global__ __launch_bounds__(512, 2) void k_scores(const u16* __restrict__ Qb, const u16* __restrict__ Kb,
                                                   u16* __restrict__ Pb, float* __restrict__ sums) {
    __shared__ __align__(16) u16 lds[65536];
    const int l  = xcd_swz(blockIdx.x, 32);
    const int bx = l & 7;
    const int by = (l >> 3) & 7;
    const int b  = l >> 6;
    const int m0 = by * 256, n0 = bx * 256;
    const u16* A = Qb + ((size_t)b * S_LEN + m0) * DQ;
    const u16* B = Kb + ((size_t)b * S_LEN + n0) * DQ;

    f32x4 acc[8][4];
#pragma unroll
    for (int i = 0; i < 8; ++i)
#pragma unroll
        for (int j = 0; j < 4; ++j) acc[i][j] = (f32x4)0.0f;

    const int tid = threadIdx.x;
    gemm256(A, B, lds, lds + 32768, acc, tid);

    const float scale = 0.044194173824159216f; // 1/sqrt(512)
    const int lane = tid & 63, w = tid >> 6;
    const int wr = w >> 2, wc = w & 3;
    const int l16 = lane & 15, quad = lane >> 4;
    u16* prow = Pb + (size_t)(b * S_LEN + m0) * S_LEN;

    float psum[8][4];
#pragma unroll
    for (int i = 0; i < 8; ++i)
#pragma unroll
        for (int r = 0; r < 4; ++r) psum[i][r] = 0.0f;

#pragma unroll
    for (int i = 0; i < 8; ++i)
#pragma unroll
        for (int j = 0; j < 4; ++j)
#pragma unroll
            for (int r = 0; r < 4; ++r) {
                int gm = wr * 128 + i * 16 + quad * 4 + r;
                int gn = n0 + wc * 64 + j * 16 + l16;
                float e = __expf(acc[i][j][r] * scale);
                u16 pbv = f2bf(e);
                prow[(size_t)gm * S_LEN + gn] = pbv;
                psum[i][r] += bf2f(pbv);
            }

    float* sums_row = sums + b * S_LEN + m0 + wr * 128;
#pragma unroll
    for (int i = 0; i < 8; ++i)
#pragma unroll
        for (int r = 0; r < 4; ++r) {
            float v = psum[i][r];
            v += __shfl_xor(v, 1);
            v += __shfl_xor(v, 2);
            v += __shfl_xor(v, 4);
            v += __shfl_xor(v, 8);
            if (l16 == 0) atomicAdd(&sums_row[i * 16 + quad * 4 + r], v);
        }
}

// ======== k_pv: 128x128 tile, 8 waves, BK=64, TRIPLE-buffered, counted vmcnt ========
// A = Pb panel [128][2048], B = VT panel [128][2048] (row stride S_LEN).
// Half-tile = 64 rows x 64 cols -> 1 async16/thread = 1 load/wave. 4 halves/tile.
// Pipeline: at tile kt read buf kt%3; stage tile kt+2; tile-end s_waitcnt vmcnt(4)
// (kt+1's loads guaranteed, kt+2's 4 stay in flight) + raw s_barrier. Never drains to 0.
__device__ __forceinline__ void stage_pv(const u16* __restrict__ G, u16* buf,
                                         int kcol, int h, int tid) {
    int c   = tid;                 // 16B chunk 0..511 within half (64 rows x 8 chunks)
    int r   = c >> 3;              // row 0..63
    int p   = c & 7;               // physical chunk
    int lch = p ^ (r & 7);         // logical chunk (pre-swizzled source)
    async16(G + (size_t)(h * 64 + r) * S_LEN + kcol + lch * 8,
            buf + h * 4096 + c * 8);
}

// nwg = 256 = (b=4)x(by=16)x(bx=4); chunk 32/XCD; 1 block/CU so 96 KiB LDS is free.
__global__ __launch_bounds__(512, 2) void k_pv(const u16* __restrict__ Pb, const u16* __restrict__ VT,
                                               const float* __restrict__ sums,
                                               float* __restrict__ probs,
                                               float* __restrict__ wout) {
    __shared__ __align__(16) u16 lds[49152];   // 96 KiB: A 3x8192 | B 3x8192
    u16* ldsA = lds;
    u16* ldsB = lds + 24576;
    const int l  = xcd_swz(blockIdx.x, 32);
    const int bx = l & 3;
    const int by = (l >> 2) & 15;
    const int b  = l >> 6;
    const int m0 = by * 128, n0 = bx * 128;
    const u16* A = Pb + (size_t)(b * S_LEN + m0) * S_LEN;
    const u16* B = VT + (size_t)b * DQ * S_LEN + (size_t)n0 * S_LEN;

    const int tid  = threadIdx.x;
    const int lane = tid & 63;
    const int w    = tid >> 6;
    const int wr   = w >> 2;       // 0..1 -> rows wr*64..+63
    const int wc   = w & 3;        // 0..3 -> cols wc*32..+31
    const int l16  = lane & 15;
    const int quad = lane >> 4;
    const int p0   = quad ^ (l16 & 7);
    const int a0   = (wr * 64 + l16) * 64 + p0 * 8;
    const int a1   = (wr * 64 + l16) * 64 + (p0 ^ 4) * 8;
    const int b0   = (wc * 32 + l16) * 64 + p0 * 8;
    const int b1   = (wc * 32 + l16) * 64 + (p0 ^ 4) * 8;

    f32x4 acc[4][2];
#pragma unroll
    for (int i = 0; i < 4; ++i)
#pragma unroll
        for (int j = 0; j < 2; ++j) acc[i][j] = (f32x4)0.0f;

    // prologue: stage tiles 0 and 1 (8 loads/wave); guarantee tile 0, keep tile 1 in flight
    stage_pv(A, ldsA, 0, 0, tid);          stage_pv(A, ldsA, 0, 1, tid);
    stage_pv(B, ldsB, 0, 0, tid);          stage_pv(B, ldsB, 0, 1, tid);
    stage_pv(A, ldsA + 8192, 64, 0, tid);  stage_pv(A, ldsA + 8192, 64, 1, tid);
    stage_pv(B, ldsB + 8192, 64, 0, tid);  stage_pv(B, ldsB + 8192, 64, 1, tid);
    asm volatile("s_waitcnt vmcnt(4)" ::: "memory");
    __builtin_amdgcn_s_barrier();
    __builtin_amdgcn_sched_barrier(0);

    int rb = 0;                            // read-buffer index = kt % 3
    for (int kt = 0; kt < 32; ++kt) {
        const u16* rdA = ldsA + rb * 8192;
        const u16* rdB = ldsB + rb * 8192;
        if (kt < 30) {
            int wbi = rb >= 1 ? rb - 1 : 2;   // (kt+2) % 3
            u16* wA = ldsA + wbi * 8192;
            u16* wB = ldsB + wbi * 8192;
            const int kc = (kt + 2) * 64;
            stage_pv(A, wA, kc, 0, tid);
            stage_pv(A, wA, kc, 1, tid);
            stage_pv(B, wB, kc, 0, tid);
            stage_pv(B, wB, kc, 1, tid);
        }

        bf16x8 a[4][2], bbf[2];
#pragma unroll
        for (int i = 0; i < 4; ++i) {
            a[i][0] = *(const bf16x8*)(rdA + a0 + i * 1024);
            a[i][1] = *(const bf16x8*)(rdA + a1 + i * 1024);
        }
        bbf[0] = *(const bf16x8*)(rdB + b0);
        bbf[1] = *(const bf16x8*)(rdB + b1);
        __builtin_amdgcn_s_setprio(1);
#pragma unroll
        for (int i = 0; i < 4; ++i) {
            acc[i][0] = __builtin_amdgcn_mfma_f32_16x16x32_bf16(a[i][0], bbf[0], acc[i][0], 0, 0, 0);
            acc[i][0] = __builtin_amdgcn_mfma_f32_16x16x32_bf16(a[i][1], bbf[1], acc[i][0], 0, 0, 0);
        }
        __builtin_amdgcn_s_setprio(0);

        bbf[0] = *(const bf16x8*)(rdB + b0 + 1024);
        bbf[1] = *(const bf16x8*)(rdB + b1 + 1024);
        __builtin_amdgcn_s_setprio(1);
#pragma unroll
        for (int i = 0; i < 4; ++i) {
            acc[i][1] = __builtin_amdgcn_mfma_f32_16x16x32_bf16(a[i][0], bbf[0], acc[i][1], 0, 0, 0);
            acc[i][1] = __builtin_amdgcn_mfma_f32_16x16x32_bf16(a[i][1], bbf[1], acc[i][1], 0, 0, 0);
        }
        __builtin_amdgcn_s_setprio(0);

        if (kt < 31) {
            if (kt < 30) asm volatile("s_waitcnt vmcnt(4)" ::: "memory");
            else         asm volatile("s_waitcnt vmcnt(0)" ::: "memory");
            __builtin_amdgcn_s_barrier();
            __builtin_amdgcn_sched_barrier(0);
        }
        rb = (rb == 2) ? 0 : rb + 1;
    }

    // inv table (128 rows) in buf0 region (its readers all finished before kt=30's barrier)
    float* ldsInv = (float*)lds;
    if (tid < 128) ldsInv[tid] = 1.0f / sums[b * S_LEN + m0 + tid];
    __syncthreads();

    float* outb = wout + (size_t)b * S_LEN * DQ;
#pragma unroll
    for (int i = 0; i < 4; ++i) {
#pragma unroll
        for (int r = 0; r < 4; ++r) {
            int lm = wr * 64 + i * 16 + quad * 4 + r;
            float inv = ldsInv[lm];
#pragma unroll
            for (int j = 0; j < 2; ++j) {
                int gn = n0 + wc * 32 + j * 16 + l16;
                outb[(size_t)(m0 + lm) * DQ + gn] = acc[i][j][r] * inv;
            }
        }
    }

    // normalized probs for this block's 128x512 col-slice, from global Pb (L2)
    const u16* Psl = Pb + (size_t)(b * S_LEN + m0) * S_LEN + bx * 512;
    float* Pro = probs + ((size_t)b * S_LEN + m0) * S_LEN + bx * 512;
#pragma unroll
    for (int it = 0; it < 16; ++it) {
        int idx = it * 512 + tid;       // 8192 chunks of 8 elems
        int r  = idx >> 6;              // row 0..127
        int cc = (idx & 63) << 3;       // col 0..511 step 8
        float inv = ldsInv[r];
        bf16x8 vv = *(const bf16x8*)(Psl + (size_t)r * S_LEN + cc);
        f32x4 o0, o1;
        o0.x = bf2f((u16)vv[0]) * inv;
        o0.y = bf2f((u16)vv[1]) * inv;
        o0.z = bf2f((u16)vv[2]) * inv;
        o0.w = bf2f((u16)vv[3]) * inv;
        o1.x = bf2f((u16)vv[4]) * inv;
        o1.y = bf2f((u16)vv[5]) * inv;
        o1.z = bf2f((u16)vv[6]) * inv;
        o1.w = bf2f((u16)vv[7]) * inv;
        float* dst = Pro + (size_t)r * S_LEN + cc;
        *(f32x4*)(dst) = o0;
        *(f32x4*)(dst + 4) = o1;
    }
}

extern "C" void kernel_launch(void* const* d_in, const int* in_sizes, int n_in,
                              void* d_out, int out_size, void* d_ws, size_t ws_size,
                              hipStream_t stream) {
    const float* x  = (const float*)d_in[0];
    const float* Wq = (const float*)d_in[1];
    const float* bq = (const float*)d_in[2];
    const float* Wk = (const float*)d_in[3];
    const float* bk = (const float*)d_in[4];
    const float* Wv = (const float*)d_in[5];
    const float* bv = (const float*)d_in[6];

    char* ws = (char*)d_ws;
    u16* xb  = (u16*)(ws);                 // x bf16        [8192][512]   8.39 MB
    u16* Wb  = (u16*)(ws + 8388608);       // Wq,Wk,Wv bf16 3x[512][512]  1.57 MB
    u16* Qb  = (u16*)(ws + 9961472);       // Q bf16        [8192][512]
    u16* Kb  = (u16*)(ws + 18350080);      // K bf16        [8192][512]
    u16* VTb = (u16*)(ws + 35127296);      // V^T bf16      [4][512][2048]
    u16* Pb  = (u16*)(ws + 43515904);      // e bf16 (unnormalized) [8192][2048]  33.6 MB
    float* sums = (float*)(ws + 77070336); // [8192] fp32 row sums (atomic)
    float* probs = (float*)d_out;                        // [4][2048][2048]
    float* wout  = (float*)d_out + 16777216;             // [4][2048][512]

    k_cvt_all<<<4872, 256, 0, stream>>>(x, Wq, Wk, Wv, xb, Wb, sums);
    k_proj<<<192, 512, 0, stream>>>(xb, Wb, bq, bk, bv, Qb, VTb);
    k_scores<<<256, 512, 0, stream>>>(Qb, Kb, Pb, sums);
    k_pv<<<256, 512, 0, stream>>>(Pb, VTb, sums, probs, wout);
}

// Round 7
// 177.855 us; speedup vs baseline: 1.1667x; 1.0244x over previous
//
#include <hip/hip_runtime.h>
#include <hip/hip_bf16.h>

typedef unsigned short u16;
typedef short bf16x8 __attribute__((ext_vector_type(8)));
typedef float f32x4 __attribute__((ext_vector_type(4)));

#define S_LEN 2048
#define DQ 512
#define NBATCH 4

__device__ __forceinline__ u16 f2bf(float f) {
    __hip_bfloat16 h = __float2bfloat16(f);
    return *reinterpret_cast<u16*>(&h);
}
__device__ __forceinline__ float bf2f(u16 u) {
    unsigned v = ((unsigned)u) << 16;
    union { unsigned u; float f; } c; c.u = v; return c.f;
}

__device__ __forceinline__ void async16(const u16* g, u16* l) {
    __builtin_amdgcn_global_load_lds(
        (__attribute__((address_space(1))) void*)g,
        (__attribute__((address_space(3))) void*)l, 16, 0, 0);
}

// XCD-chunked bijective swizzle (T1): hardware assigns dispatch id d -> XCD d%8.
__device__ __forceinline__ int xcd_swz(int bid, int chunk) {
    return (bid & 7) * chunk + (bid >> 3);
}

// -------- fp32 -> bf16 convert: x + Wq + Wk + Wv; tail blocks zero the sums buffer --------
__global__ __launch_bounds__(256) void k_cvt_all(const float* __restrict__ x,
                                                 const float* __restrict__ wq,
                                                 const float* __restrict__ wk,
                                                 const float* __restrict__ wv,
                                                 u16* __restrict__ xb, u16* __restrict__ wb,
                                                 float* __restrict__ sums) {
    int bid = blockIdx.x;
    if (bid >= 4864) {  // 8 blocks zero sums[8192]
        int i = (bid - 4864) * 256 + threadIdx.x;
        *(f32x4*)(sums + (size_t)i * 4) = (f32x4)0.0f;
        return;
    }
    const float* src;
    u16* dst;
    int i;
    if (bid < 4096)      { src = x;  dst = xb;          i = bid * 256 + threadIdx.x; }
    else if (bid < 4352) { src = wq; dst = wb;          i = (bid - 4096) * 256 + threadIdx.x; }
    else if (bid < 4608) { src = wk; dst = wb + 262144; i = (bid - 4352) * 256 + threadIdx.x; }
    else                 { src = wv; dst = wb + 524288; i = (bid - 4608) * 256 + threadIdx.x; }
    f32x4 v = *(const f32x4*)(src + (size_t)i * 4);
    ushort4 o;
    o.x = f2bf(v.x); o.y = f2bf(v.y); o.z = f2bf(v.z); o.w = f2bf(v.w);
    *(ushort4*)(dst + (size_t)i * 4) = o;
}

// ================= 256x256 double-buffered GEMM core (BK=64, 8 waves) =================
// LDS layout per matrix buffer: [256 rows][64 cols] bf16, 128 B/row = 8 chunks of 16 B.
// XOR swizzle (T2/st-16x32): physical chunk = logical chunk ^ (row & 7).
// Staged via global_load_lds with LINEAR LDS dest + pre-swizzled GLOBAL source (rule 21).
__device__ __forceinline__ void stage_unit(const u16* __restrict__ G, u16* buf,
                                           int kcol, int h, int tid) {
#pragma unroll
    for (int q = 0; q < 2; ++q) {
        int c   = q * 512 + tid;          // 16B chunk id 0..1023 within half-tile
        int r   = c >> 3;                 // row 0..127 within half
        int p   = c & 7;                  // physical chunk within row
        int lch = p ^ (r & 7);            // logical (global) chunk
        async16(G + (size_t)(h * 128 + r) * DQ + kcol + lch * 8,
                buf + h * 8192 + c * 8);  // linear dest: wave-uniform base + lane*16B
    }
}

// A,B: row-major panels [256][512] (row stride DQ). C = A * B^T on 256x256 tile.
// All 4 next-tile stages issued in the first two MFMA groups -> later loads get
// ~2-3 groups (~300 cyc) of compute cover before the tile-end drain.
__device__ __forceinline__ void gemm256(const u16* __restrict__ A, const u16* __restrict__ B,
                                        u16* ldsA, u16* ldsB, f32x4 acc[8][4], int tid) {
    const int lane = tid & 63;
    const int w    = tid >> 6;
    const int wr   = w >> 2;
    const int wc   = w & 3;
    const int l16  = lane & 15;
    const int quad = lane >> 4;
    const int p0   = quad ^ (l16 & 7);
    const int a0   = (wr * 128 + l16) * 64 + p0 * 8;
    const int a1   = (wr * 128 + l16) * 64 + (p0 ^ 4) * 8;
    const int b0   = (wc * 64 + l16) * 64 + p0 * 8;
    const int b1   = (wc * 64 + l16) * 64 + (p0 ^ 4) * 8;

    stage_unit(A, ldsA, 0, 0, tid);
    stage_unit(A, ldsA, 0, 1, tid);
    stage_unit(B, ldsB, 0, 0, tid);
    stage_unit(B, ldsB, 0, 1, tid);
    __syncthreads();

    for (int kt = 0; kt < 8; ++kt) {
        const u16* rdA = ldsA + (kt & 1) * 16384;
        const u16* rdB = ldsB + (kt & 1) * 16384;
        u16* wrA = ldsA + ((kt + 1) & 1) * 16384;
        u16* wrB = ldsB + ((kt + 1) & 1) * 16384;
        const int  kc = (kt + 1) * 64;
        const bool pf = kt < 7;
        bf16x8 a[4][2], bbf[2][2];

        // ---- G0: stage A-half0+half1(kt+1); read A m0-3 + B n0-1; MFMA ----
        if (pf) { stage_unit(A, wrA, kc, 0, tid); stage_unit(A, wrA, kc, 1, tid); }
#pragma unroll
        for (int i = 0; i < 4; ++i) {
            a[i][0] = *(const bf16x8*)(rdA + a0 + i * 1024);
            a[i][1] = *(const bf16x8*)(rdA + a1 + i * 1024);
        }
#pragma unroll
        for (int j = 0; j < 2; ++j) {
            bbf[j][0] = *(const bf16x8*)(rdB + b0 + j * 1024);
            bbf[j][1] = *(const bf16x8*)(rdB + b1 + j * 1024);
        }
        __builtin_amdgcn_s_setprio(1);
#pragma unroll
        for (int i = 0; i < 4; ++i)
#pragma unroll
            for (int j = 0; j < 2; ++j) {
                acc[i][j] = __builtin_amdgcn_mfma_f32_16x16x32_bf16(a[i][0], bbf[j][0], acc[i][j], 0, 0, 0);
                acc[i][j] = __builtin_amdgcn_mfma_f32_16x16x32_bf16(a[i][1], bbf[j][1], acc[i][j], 0, 0, 0);
            }
        __builtin_amdgcn_s_setprio(0);

        // ---- G1: stage B-half0+half1(kt+1); read B n2-3; MFMA m0-3 x n2-3 ----
        if (pf) { stage_unit(B, wrB, kc, 0, tid); stage_unit(B, wrB, kc, 1, tid); }
#pragma unroll
        for (int j = 0; j < 2; ++j) {
            bbf[j][0] = *(const bf16x8*)(rdB + b0 + (2 + j) * 1024);
            bbf[j][1] = *(const bf16x8*)(rdB + b1 + (2 + j) * 1024);
        }
        __builtin_amdgcn_s_setprio(1);
#pragma unroll
        for (int i = 0; i < 4; ++i)
#pragma unroll
            for (int j = 0; j < 2; ++j) {
                acc[i][2 + j] = __builtin_amdgcn_mfma_f32_16x16x32_bf16(a[i][0], bbf[j][0], acc[i][2 + j], 0, 0, 0);
                acc[i][2 + j] = __builtin_amdgcn_mfma_f32_16x16x32_bf16(a[i][1], bbf[j][1], acc[i][2 + j], 0, 0, 0);
            }
        __builtin_amdgcn_s_setprio(0);

        // ---- G2: read A m4-7; MFMA m4-7 x n2-3 ----
#pragma unroll
        for (int i = 0; i < 4; ++i) {
            a[i][0] = *(const bf16x8*)(rdA + a0 + (4 + i) * 1024);
            a[i][1] = *(const bf16x8*)(rdA + a1 + (4 + i) * 1024);
        }
        __builtin_amdgcn_s_setprio(1);
#pragma unroll
        for (int i = 0; i < 4; ++i)
#pragma unroll
            for (int j = 0; j < 2; ++j) {
                acc[4 + i][2 + j] = __builtin_amdgcn_mfma_f32_16x16x32_bf16(a[i][0], bbf[j][0], acc[4 + i][2 + j], 0, 0, 0);
                acc[4 + i][2 + j] = __builtin_amdgcn_mfma_f32_16x16x32_bf16(a[i][1], bbf[j][1], acc[4 + i][2 + j], 0, 0, 0);
            }
        __builtin_amdgcn_s_setprio(0);

        // ---- G3: read B n0-1 again; MFMA m4-7 x n0-1 ----
#pragma unroll
        for (int j = 0; j < 2; ++j) {
            bbf[j][0] = *(const bf16x8*)(rdB + b0 + j * 1024);
            bbf[j][1] = *(const bf16x8*)(rdB + b1 + j * 1024);
        }
        __builtin_amdgcn_s_setprio(1);
#pragma unroll
        for (int i = 0; i < 4; ++i)
#pragma unroll
            for (int j = 0; j < 2; ++j) {
                acc[4 + i][j] = __builtin_amdgcn_mfma_f32_16x16x32_bf16(a[i][0], bbf[j][0], acc[4 + i][j], 0, 0, 0);
                acc[4 + i][j] = __builtin_amdgcn_mfma_f32_16x16x32_bf16(a[i][1], bbf[j][1], acc[4 + i][j], 0, 0, 0);
            }
        __builtin_amdgcn_s_setprio(0);

        __syncthreads();
    }
}

// -------- projection: z in {Q,K,V}; 256x256 tiles; nwg = 192 = (z=3)x(by=32)x(bx=2) --------
__global__ __launch_bounds__(512, 2) void k_proj(const u16* __restrict__ xb, const u16* __restrict__ Wb,
                                                 const float* __restrict__ bq, const float* __restrict__ bk,
                                                 const float* __restrict__ bv, u16* __restrict__ out,
                                                 u16* __restrict__ VT) {
    __shared__ __align__(16) u16 lds[65536];   // 128 KiB: A 2x16384 | B 2x16384
    const int l  = xcd_swz(blockIdx.x, 24);
    const int bx = l & 1;
    const int by = (l >> 1) & 31;
    const int z  = l >> 6;
    const int m0 = by * 256, n0 = bx * 256;
    const u16* A = xb + (size_t)m0 * DQ;
    const u16* B = Wb + (size_t)z * DQ * DQ + (size_t)n0 * DQ;
    const float* bias = (z == 0) ? bq : (z == 1) ? bk : bv;

    f32x4 acc[8][4];
#pragma unroll
    for (int i = 0; i < 8; ++i)
#pragma unroll
        for (int j = 0; j < 4; ++j) acc[i][j] = (f32x4)0.0f;

    const int tid = threadIdx.x;
    gemm256(A, B, lds, lds + 32768, acc, tid);

    const int lane = tid & 63, w = tid >> 6;
    const int wr = w >> 2, wc = w & 3;
    const int l16 = lane & 15, quad = lane >> 4;

    if (z < 2) {
        u16* outz = out + (size_t)z * 8192 * DQ;
#pragma unroll
        for (int j = 0; j < 4; ++j) {
            int gn = n0 + wc * 64 + j * 16 + l16;
            float bv_ = bias[gn];
#pragma unroll
            for (int i = 0; i < 8; ++i)
#pragma unroll
                for (int r = 0; r < 4; ++r) {
                    int gm = m0 + wr * 128 + i * 16 + quad * 4 + r;
                    outz[(size_t)gm * DQ + gn] = f2bf(acc[i][j][r] + bv_);
                }
        }
    } else {
        const int bb_ = m0 >> 11;
        u16* VTb_ = VT + (size_t)bb_ * DQ * S_LEN;
#pragma unroll
        for (int j = 0; j < 4; ++j) {
            int gn = n0 + wc * 64 + j * 16 + l16;
            float bv_ = bias[gn];
#pragma unroll
            for (int i = 0; i < 8; ++i) {
                int t0 = (m0 & 2047) + wr * 128 + i * 16 + quad * 4;
                ushort4 o;
                o.x = f2bf(acc[i][j][0] + bv_);
                o.y = f2bf(acc[i][j][1] + bv_);
                o.z = f2bf(acc[i][j][2] + bv_);
                o.w = f2bf(acc[i][j][3] + bv_);
                *(ushort4*)(VTb_ + (size_t)gn * S_LEN + t0) = o;
            }
        }
    }
}

// -------- scores: 256x256 tiles; e=exp(QK^T*scale)->bf16 Pb + atomic row sums --------
__global__ __launch_bounds__(512, 2) void k_scores(const u16* __restrict__ Qb, const u16* __restrict__ Kb,
                                                   u16* __restrict__ Pb, float* __restrict__ sums) {
    __shared__ __align__(16) u16 lds[65536];
    const int l  = xcd_swz(blockIdx.x, 32);
    const int bx = l & 7;
    const int by = (l >> 3) & 7;
    const int b  = l >> 6;
    const int m0 = by * 256, n0 = bx * 256;
    const u16* A = Qb + ((size_t)b * S_LEN + m0) * DQ;
    const u16* B = Kb + ((size_t)b * S_LEN + n0) * DQ;

    f32x4 acc[8][4];
#pragma unroll
    for (int i = 0; i < 8; ++i)
#pragma unroll
        for (int j = 0; j < 4; ++j) acc[i][j] = (f32x4)0.0f;

    const int tid = threadIdx.x;
    gemm256(A, B, lds, lds + 32768, acc, tid);

    const float scale = 0.044194173824159216f; // 1/sqrt(512)
    const int lane = tid & 63, w = tid >> 6;
    const int wr = w >> 2, wc = w & 3;
    const int l16 = lane & 15, quad = lane >> 4;
    u16* prow = Pb + (size_t)(b * S_LEN + m0) * S_LEN;

    float psum[8][4];
#pragma unroll
    for (int i = 0; i < 8; ++i)
#pragma unroll
        for (int r = 0; r < 4; ++r) psum[i][r] = 0.0f;

#pragma unroll
    for (int i = 0; i < 8; ++i)
#pragma unroll
        for (int j = 0; j < 4; ++j)
#pragma unroll
            for (int r = 0; r < 4; ++r) {
                int gm = wr * 128 + i * 16 + quad * 4 + r;
                int gn = n0 + wc * 64 + j * 16 + l16;
                float e = __expf(acc[i][j][r] * scale);
                u16 pbv = f2bf(e);
                prow[(size_t)gm * S_LEN + gn] = pbv;
                psum[i][r] += bf2f(pbv);
            }

    float* sums_row = sums + b * S_LEN + m0 + wr * 128;
#pragma unroll
    for (int i = 0; i < 8; ++i)
#pragma unroll
        for (int r = 0; r < 4; ++r) {
            float v = psum[i][r];
            v += __shfl_xor(v, 1);
            v += __shfl_xor(v, 2);
            v += __shfl_xor(v, 4);
            v += __shfl_xor(v, 8);
            if (l16 == 0) atomicAdd(&sums_row[i * 16 + quad * 4 + r], v);
        }
}

// ======== k_pv: 128x128 tile, 8 waves, BK=64, triple-buffered, counted vmcnt ========
// A = Pb panel [128][2048], B = VT panel [128][2048] (row stride S_LEN).
// The normalized-probs pass is INTERLEAVED into the K-loop: on even kt each thread
// handles one 8-elem chunk (load early, cvt+store after the MFMAs) -> the 100 MB
// probs traffic hides under the PV compute instead of running as a serial tail.
// vmcnt invariant (issue order per even iter: probs-load, stage(4), ..., stores(2)):
// tile-end vmcnt(6) leaves {2 stores + next-next stage(4)} in flight and guarantees
// the next tile's stages -- holds for both parities.
__device__ __forceinline__ void stage_pv(const u16* __restrict__ G, u16* buf,
                                         int kcol, int h, int tid) {
    int c   = tid;                 // 16B chunk 0..511 within half (64 rows x 8 chunks)
    int r   = c >> 3;              // row 0..63
    int p   = c & 7;               // physical chunk
    int lch = p ^ (r & 7);         // logical chunk (pre-swizzled source)
    async16(G + (size_t)(h * 64 + r) * S_LEN + kcol + lch * 8,
            buf + h * 4096 + c * 8);
}

// nwg = 256 = (b=4)x(by=16)x(bx=4); chunk 32/XCD; 1 block/CU so ~97 KiB LDS is free.
__global__ __launch_bounds__(512, 2) void k_pv(const u16* __restrict__ Pb, const u16* __restrict__ VT,
                                               const float* __restrict__ sums,
                                               float* __restrict__ probs,
                                               float* __restrict__ wout) {
    __shared__ __align__(16) u16 lds[49408];   // A 3x8192 | B 3x8192 | inv 128 f32
    u16* ldsA = lds;
    u16* ldsB = lds + 24576;
    float* ldsInv = (float*)(lds + 49152);
    const int l  = xcd_swz(blockIdx.x, 32);
    const int bx = l & 3;
    const int by = (l >> 2) & 15;
    const int b  = l >> 6;
    const int m0 = by * 128, n0 = bx * 128;
    const u16* A = Pb + (size_t)(b * S_LEN + m0) * S_LEN;
    const u16* B = VT + (size_t)b * DQ * S_LEN + (size_t)n0 * S_LEN;
    const u16* Psl = Pb + (size_t)(b * S_LEN + m0) * S_LEN + bx * 512;
    float* Pro = probs + ((size_t)b * S_LEN + m0) * S_LEN + bx * 512;

    const int tid  = threadIdx.x;
    const int lane = tid & 63;
    const int w    = tid >> 6;
    const int wr   = w >> 2;       // 0..1 -> rows wr*64..+63
    const int wc   = w & 3;        // 0..3 -> cols wc*32..+31
    const int l16  = lane & 15;
    const int quad = lane >> 4;
    const int p0   = quad ^ (l16 & 7);
    const int a0   = (wr * 64 + l16) * 64 + p0 * 8;
    const int a1   = (wr * 64 + l16) * 64 + (p0 ^ 4) * 8;
    const int b0   = (wc * 32 + l16) * 64 + p0 * 8;
    const int b1   = (wc * 32 + l16) * 64 + (p0 ^ 4) * 8;

    f32x4 acc[4][2];
#pragma unroll
    for (int i = 0; i < 4; ++i)
#pragma unroll
        for (int j = 0; j < 2; ++j) acc[i][j] = (f32x4)0.0f;

    // prologue: inv-table load, stage tiles 0 and 1; guarantee tile 0, keep tile 1 in flight
    float sv = 1.0f;
    if (tid < 128) sv = sums[b * S_LEN + m0 + tid];
    stage_pv(A, ldsA, 0, 0, tid);          stage_pv(A, ldsA, 0, 1, tid);
    stage_pv(B, ldsB, 0, 0, tid);          stage_pv(B, ldsB, 0, 1, tid);
    stage_pv(A, ldsA + 8192, 64, 0, tid);  stage_pv(A, ldsA + 8192, 64, 1, tid);
    stage_pv(B, ldsB + 8192, 64, 0, tid);  stage_pv(B, ldsB + 8192, 64, 1, tid);
    if (tid < 128) ldsInv[tid] = 1.0f / sv;
    asm volatile("s_waitcnt vmcnt(4) lgkmcnt(0)" ::: "memory");
    __builtin_amdgcn_s_barrier();
    __builtin_amdgcn_sched_barrier(0);

    int rb = 0;                            // read-buffer index = kt % 3
    for (int kt = 0; kt < 32; ++kt) {
        const u16* rdA = ldsA + rb * 8192;
        const u16* rdB = ldsB + rb * 8192;

        // interleaved probs chunk (even kt): issue load early, consume after MFMAs
        const bool do_probs = (kt & 1) == 0;
        bf16x8 pvv;
        float pinv = 0.0f;
        float* pdst = nullptr;
        if (do_probs) {
            int idx = (kt >> 1) * 512 + tid;   // chunk-iter 0..15
            int r  = idx >> 6;                 // row 0..127
            int cc = (idx & 63) << 3;          // col 0..511 step 8
            pvv  = *(const bf16x8*)(Psl + (size_t)r * S_LEN + cc);
            pinv = ldsInv[r];
            pdst = Pro + (size_t)r * S_LEN + cc;
        }

        if (kt < 30) {
            int wbi = rb >= 1 ? rb - 1 : 2;   // (kt+2) % 3
            u16* wA = ldsA + wbi * 8192;
            u16* wB = ldsB + wbi * 8192;
            const int kc = (kt + 2) * 64;
            stage_pv(A, wA, kc, 0, tid);
            stage_pv(A, wA, kc, 1, tid);
            stage_pv(B, wB, kc, 0, tid);
            stage_pv(B, wB, kc, 1, tid);
        }

        bf16x8 a[4][2], bbf[2];
#pragma unroll
        for (int i = 0; i < 4; ++i) {
            a[i][0] = *(const bf16x8*)(rdA + a0 + i * 1024);
            a[i][1] = *(const bf16x8*)(rdA + a1 + i * 1024);
        }
        bbf[0] = *(const bf16x8*)(rdB + b0);
        bbf[1] = *(const bf16x8*)(rdB + b1);
        __builtin_amdgcn_s_setprio(1);
#pragma unroll
        for (int i = 0; i < 4; ++i) {
            acc[i][0] = __builtin_amdgcn_mfma_f32_16x16x32_bf16(a[i][0], bbf[0], acc[i][0], 0, 0, 0);
            acc[i][0] = __builtin_amdgcn_mfma_f32_16x16x32_bf16(a[i][1], bbf[1], acc[i][0], 0, 0, 0);
        }
        __builtin_amdgcn_s_setprio(0);

        bbf[0] = *(const bf16x8*)(rdB + b0 + 1024);
        bbf[1] = *(const bf16x8*)(rdB + b1 + 1024);
        __builtin_amdgcn_s_setprio(1);
#pragma unroll
        for (int i = 0; i < 4; ++i) {
            acc[i][1] = __builtin_amdgcn_mfma_f32_16x16x32_bf16(a[i][0], bbf[0], acc[i][1], 0, 0, 0);
            acc[i][1] = __builtin_amdgcn_mfma_f32_16x16x32_bf16(a[i][1], bbf[1], acc[i][1], 0, 0, 0);
        }
        __builtin_amdgcn_s_setprio(0);

        if (do_probs) {
            f32x4 o0, o1;
            o0.x = bf2f((u16)pvv[0]) * pinv;
            o0.y = bf2f((u16)pvv[1]) * pinv;
            o0.z = bf2f((u16)pvv[2]) * pinv;
            o0.w = bf2f((u16)pvv[3]) * pinv;
            o1.x = bf2f((u16)pvv[4]) * pinv;
            o1.y = bf2f((u16)pvv[5]) * pinv;
            o1.z = bf2f((u16)pvv[6]) * pinv;
            o1.w = bf2f((u16)pvv[7]) * pinv;
            *(f32x4*)(pdst) = o0;
            *(f32x4*)(pdst + 4) = o1;
        }

        if (kt < 31) {
            if (kt < 30) asm volatile("s_waitcnt vmcnt(6)" ::: "memory");
            else         asm volatile("s_waitcnt vmcnt(2)" ::: "memory");
            __builtin_amdgcn_s_barrier();
            __builtin_amdgcn_sched_barrier(0);
        }
        rb = (rb == 2) ? 0 : rb + 1;
    }

    // wout epilogue (ldsInv written in prologue; no post-loop barrier needed)
    float* outb = wout + (size_t)b * S_LEN * DQ;
#pragma unroll
    for (int i = 0; i < 4; ++i) {
#pragma unroll
        for (int r = 0; r < 4; ++r) {
            int lm = wr * 64 + i * 16 + quad * 4 + r;
            float inv = ldsInv[lm];
#pragma unroll
            for (int j = 0; j < 2; ++j) {
                int gn = n0 + wc * 32 + j * 16 + l16;
                outb[(size_t)(m0 + lm) * DQ + gn] = acc[i][j][r] * inv;
            }
        }
    }
}

extern "C" void kernel_launch(void* const* d_in, const int* in_sizes, int n_in,
                              void* d_out, int out_size, void* d_ws, size_t ws_size,
                              hipStream_t stream) {
    const float* x  = (const float*)d_in[0];
    const float* Wq = (const float*)d_in[1];
    const float* bq = (const float*)d_in[2];
    const float* Wk = (const float*)d_in[3];
    const float* bk = (const float*)d_in[4];
    const float* Wv = (const float*)d_in[5];
    const float* bv = (const float*)d_in[6];

    char* ws = (char*)d_ws;
    u16* xb  = (u16*)(ws);                 // x bf16        [8192][512]   8.39 MB
    u16* Wb  = (u16*)(ws + 8388608);       // Wq,Wk,Wv bf16 3x[512][512]  1.57 MB
    u16* Qb  = (u16*)(ws + 9961472);       // Q bf16        [8192][512]
    u16* Kb  = (u16*)(ws + 18350080);      // K bf16        [8192][512]
    u16* VTb = (u16*)(ws + 35127296);      // V^T bf16      [4][512][2048]
    u16* Pb  = (u16*)(ws + 43515904);      // e bf16 (unnormalized) [8192][2048]  33.6 MB
    float* sums = (float*)(ws + 77070336); // [8192] fp32 row sums (atomic)
    float* probs = (float*)d_out;                        // [4][2048][2048]
    float* wout  = (float*)d_out + 16777216;             // [4][2048][512]

    k_cvt_all<<<4872, 256, 0, stream>>>(x, Wq, Wk, Wv, xb, Wb, sums);
    k_proj<<<192, 512, 0, stream>>>(xb, Wb, bq, bk, bv, Qb, VTb);
    k_scores<<<256, 512, 0, stream>>>(Qb, Kb, Pb, sums);
    k_pv<<<256, 512, 0, stream>>>(Pb, VTb, sums, probs, wout);
}